// Round 4
// baseline (292.296 us; speedup 1.0000x reference)
//
#include <hip/hip_runtime.h>

#pragma clang fp contract(off)

#define TOLD 60000
#define TNEW 60000
#define NVERT 30000
#define MAXSTEPS 300
#define THSZ 131072                  // tet-key hash slots (exact, CAS)
#define FHSZ 524288                  // face-key exact CAS table slots
#define EMPTY64 0xFFFFFFFFFFFFFFFFULL
#define NWGC 235                     // cooperative-tail workgroups (<= resident capacity)
#define NWGP 60                      // prio partition WGs (500 verts each)
#define VRANGE 500

// workspace layout: [0xFF-init region][rest]
#define OFF_TKEYS    0u              // 131072*8 = 1,048,576
#define OFF_FTAB     1048576u        // 524288*8 = 4,194,304
#define OFF_TVALS    5242880u        // 131072*4 = 524,288
#define OFF_NBR      5767168u        // 240000*4 = 960,000
#define FF_BYTES     6727168u        // end of 0xFF region
#define OFF_CNT      6727168u        // 256 B (zeroed by k_old_all)
#define OFF_PRIO     6727424u        // 120,000 (fully written by k_prio_resolve)
#define OFF_IDXOLD   6847424u        // 960,000 (16B aligned)
#define OFF_CUR      7807424u        // 240,000
#define OFF_REM      8047424u        // 240,000
#define OFF_DEGEN    8287424u        // 240,000
#define OFF_LISTA    8527424u        // 240,000
#define OFF_LISTB    8767424u        // 240,000
#define OFF_TV4      9007424u        // 2,880,000 (3 float4/tet: M row + v0 comp)
#define OFF_COLD4    11887424u       // 960,000 (centroid, oel)
#define OFF_CNEW4    12847424u       // 960,000 (centroid, nel)
#define OFF_DM       13807424u       // direct-mapped face table, size = tiered by ws_size

struct P {
  const unsigned int* rawNew;
  const unsigned int* rawOld;
  const float* occ;
  const float* ncc;
  const float* verts;
  float* out;
  unsigned long long* tkeys;
  unsigned long long* ftab;
  int* counters;                     // [0]=n_walk [1]=cntA [2]=cntB [8]=bar.arrive [9]=bar.gen
  int* tvals;
  int* idxOld;
  int* nbr;
  int* prio;
  int* cur; int* rem;
  int* degen;
  int* listA; int* listB;
  float4* Tv4;
  float4* cold4;
  float4* cnew4;
  unsigned int* dm;                  // direct-mapped face ids (uninitialized is OK)
  unsigned int dmMask;               // 0 => direct-mapped pass disabled
};

__device__ __forceinline__ unsigned hash64(unsigned long long k){
  k ^= k >> 33; k *= 0xff51afd7ed558ccdULL;
  k ^= k >> 33; k *= 0xc4ceb9fe1a85ec53ULL;
  k ^= k >> 33;
  return (unsigned)k;
}
__device__ __forceinline__ void cswap(int& a, int& b){ if (a > b){ int t = a; a = b; b = t; } }

__device__ __forceinline__ int detect64(const unsigned int* raw){
  unsigned acc = 0;
  const uint4* r4 = (const uint4*)raw;
  #pragma unroll
  for (int k = 0; k < 32; ++k){ uint4 v = r4[k]; acc |= (v.y | v.w); }
  return acc == 0u;
}
__device__ __forceinline__ int ld_idx(const unsigned int* raw, int is64, int i){
  return is64 ? (int)((const long long*)raw)[i] : ((const int*)raw)[i];
}

// Exact open-addressing face insert (fallback path for DM collisions only).
__device__ __forceinline__ void face_insert(unsigned long long* ftab, int* nbr,
                                            unsigned long long fkey, int t, int l){
  unsigned long long mine = (fkey << 18) | (unsigned long long)(t * 4 + l);
  unsigned slot = hash64(fkey ^ 0x9e3779b97f4a7c15ULL) & (FHSZ - 1);
  while (true){
    unsigned long long prev = atomicCAS(&ftab[slot], EMPTY64, mine);
    if (prev == EMPTY64) return;
    if ((prev >> 18) == fkey){
      int oid = (int)(prev & 0x3FFFFULL);
      nbr[t * 4 + l] = oid >> 2;
      nbr[oid] = t;
      return;
    }
    slot = (slot + 1) & (FHSZ - 1);
  }
}

// min edge length from the 12 vertex coords already in registers; fold order
// matches the reference EDGES list exactly.
__device__ __forceinline__ float min_edge_r(
    float q0x, float q0y, float q0z, float q1x, float q1y, float q1z,
    float q2x, float q2y, float q2z, float q3x, float q3y, float q3z){
  float m = 3.402823466e+38f;
  float dx, dy, dz, d;
  dx = q0x - q1x; dy = q0y - q1y; dz = q0z - q1z; d = sqrtf((dx*dx + dy*dy) + dz*dz); m = fminf(m, d);
  dx = q0x - q2x; dy = q0y - q2y; dz = q0z - q2z; d = sqrtf((dx*dx + dy*dy) + dz*dz); m = fminf(m, d);
  dx = q0x - q3x; dy = q0y - q3y; dz = q0z - q3z; d = sqrtf((dx*dx + dy*dy) + dz*dz); m = fminf(m, d);
  dx = q1x - q2x; dy = q1y - q2y; dz = q1z - q2z; d = sqrtf((dx*dx + dy*dy) + dz*dz); m = fminf(m, d);
  dx = q1x - q3x; dy = q1y - q3y; dz = q1z - q3z; d = sqrtf((dx*dx + dy*dy) + dz*dz); m = fminf(m, d);
  dx = q2x - q3x; dy = q2y - q3y; dz = q2z - q3z; d = sqrtf((dx*dx + dy*dy) + dz*dz); m = fminf(m, d);
  return m;
}

// Old-tet pass: idx normalize, geometry, tet-key CAS (+plain value store),
// direct-mapped face id plain-writes. Fabric atomics: ~1 CAS + rare max per tet.
__global__ __launch_bounds__(256) void k_old_all(P p){
  int t = blockIdx.x * blockDim.x + threadIdx.x;
  if (blockIdx.x == 0 && threadIdx.x < 64) p.counters[threadIdx.x] = 0;
  if (t >= TOLD) return;
  int is64 = detect64(p.rawOld);
  int i0 = ld_idx(p.rawOld, is64, t * 4 + 0);
  int i1 = ld_idx(p.rawOld, is64, t * 4 + 1);
  int i2 = ld_idx(p.rawOld, is64, t * 4 + 2);
  int i3 = ld_idx(p.rawOld, is64, t * 4 + 3);
  ((int4*)p.idxOld)[t] = make_int4(i0, i1, i2, i3);

  // tet key insert; duplicate keys keep MAX tet id (dup probability ~5e-8;
  // winner plain-stores its value, dup path uses atomicMax)
  {
    int s0 = i0, s1 = i1, s2 = i2, s3 = i3;
    cswap(s0, s1); cswap(s2, s3); cswap(s0, s2); cswap(s1, s3); cswap(s1, s2);
    unsigned long long key =
        (unsigned long long)((((long long)s0 * NVERT + s1) * NVERT + s2) * NVERT + s3);
    unsigned slot = hash64(key) & (THSZ - 1);
    while (true){
      unsigned long long prev = atomicCAS(&p.tkeys[slot], EMPTY64, key);
      if (prev == EMPTY64){ p.tvals[slot] = t; break; }
      if (prev == key){ atomicMax(&p.tvals[slot], t); break; }
      slot = (slot + 1) & (THSZ - 1);
    }
  }

  // direct-mapped face id writes (racy last-wins; resolved in next kernel)
  if (p.dmMask){
    const int FO[4][3] = {{1, 2, 3}, {0, 2, 3}, {0, 1, 3}, {0, 1, 2}};
    int iv[4] = {i0, i1, i2, i3};
    #pragma unroll
    for (int l = 0; l < 4; ++l){
      int a = iv[FO[l][0]], b = iv[FO[l][1]], c = iv[FO[l][2]];
      cswap(a, b); cswap(a, c); cswap(b, c);
      unsigned long long fk = (unsigned long long)(((long long)a * NVERT + b) * NVERT + c);
      p.dm[hash64(fk) & p.dmMask] = (unsigned)(t * 4 + l);
    }
  }

  // geometry: Tinv (adjugate/det), v0, centroid, min edge length
  float q0x = p.verts[i0 * 3 + 0], q0y = p.verts[i0 * 3 + 1], q0z = p.verts[i0 * 3 + 2];
  float q1x = p.verts[i1 * 3 + 0], q1y = p.verts[i1 * 3 + 1], q1z = p.verts[i1 * 3 + 2];
  float q2x = p.verts[i2 * 3 + 0], q2y = p.verts[i2 * 3 + 1], q2z = p.verts[i2 * 3 + 2];
  float q3x = p.verts[i3 * 3 + 0], q3y = p.verts[i3 * 3 + 1], q3z = p.verts[i3 * 3 + 2];
  float e1x = q1x - q0x, e1y = q1y - q0y, e1z = q1z - q0z;
  float e2x = q2x - q0x, e2y = q2y - q0y, e2z = q2z - q0z;
  float e3x = q3x - q0x, e3y = q3y - q0y, e3z = q3z - q0z;
  float c23x = e2y * e3z - e2z * e3y;
  float c23y = e2z * e3x - e2x * e3z;
  float c23z = e2x * e3y - e2y * e3x;
  float det = e1x * c23x + e1y * c23y + e1z * c23z;
  int dg = (fabsf(det) < 1e-10f) ? 1 : 0;
  p.degen[t] = dg;
  float4 r0, r1, r2;
  if (dg){
    r0 = make_float4(1.f, 0.f, 0.f, q0x);
    r1 = make_float4(0.f, 1.f, 0.f, q0y);
    r2 = make_float4(0.f, 0.f, 1.f, q0z);
  } else {
    float inv = 1.0f / det;
    float c31x = e3y * e1z - e3z * e1y;
    float c31y = e3z * e1x - e3x * e1z;
    float c31z = e3x * e1y - e3y * e1x;
    float c12x = e1y * e2z - e1z * e2y;
    float c12y = e1z * e2x - e1x * e2z;
    float c12z = e1x * e2y - e1y * e2x;
    r0 = make_float4(c23x * inv, c23y * inv, c23z * inv, q0x);
    r1 = make_float4(c31x * inv, c31y * inv, c31z * inv, q0y);
    r2 = make_float4(c12x * inv, c12y * inv, c12z * inv, q0z);
  }
  p.Tv4[t * 3 + 0] = r0;
  p.Tv4[t * 3 + 1] = r1;
  p.Tv4[t * 3 + 2] = r2;
  float el = min_edge_r(q0x, q0y, q0z, q1x, q1y, q1z, q2x, q2y, q2z, q3x, q3y, q3z);
  p.cold4[t] = make_float4((((q0x + q1x) + q2x) + q3x) * 0.25f,
                           (((q0y + q1y) + q2y) + q3y) * 0.25f,
                           (((q0z + q1z) + q2z) + q3z) * 0.25f, el);
}

// WGs [0,NWGP): prio via LDS-max partition scan (zero fabric atomics).
// WGs [NWGP,...): face resolve via direct-mapped table; only DM collisions
// fall back to the exact CAS table.
__global__ __launch_bounds__(256) void k_prio_resolve(P p){
  __shared__ int sprio[VRANGE];
  if (blockIdx.x < NWGP){
    int base = blockIdx.x * VRANGE;
    for (int j = threadIdx.x; j < VRANGE; j += 256) sprio[j] = -1;
    __syncthreads();
    for (int t = threadIdx.x; t < TOLD; t += 256){
      int4 iv = ((const int4*)p.idxOld)[t];
      int v;
      v = iv.x - base; if ((unsigned)v < VRANGE) atomicMax(&sprio[v], 0 * TOLD + t);
      v = iv.y - base; if ((unsigned)v < VRANGE) atomicMax(&sprio[v], 1 * TOLD + t);
      v = iv.z - base; if ((unsigned)v < VRANGE) atomicMax(&sprio[v], 2 * TOLD + t);
      v = iv.w - base; if ((unsigned)v < VRANGE) atomicMax(&sprio[v], 3 * TOLD + t);
    }
    __syncthreads();
    for (int j = threadIdx.x; j < VRANGE; j += 256) p.prio[base + j] = sprio[j];
    return;
  }
  int i = (blockIdx.x - NWGP) * 256 + threadIdx.x;
  if (i >= TOLD * 4) return;
  int t = i >> 2, l = i & 3;
  int4 iv4 = ((const int4*)p.idxOld)[t];
  int iv[4] = {iv4.x, iv4.y, iv4.z, iv4.w};
  const int FO[4][3] = {{1, 2, 3}, {0, 2, 3}, {0, 1, 3}, {0, 1, 2}};
  int a = iv[FO[l][0]], b = iv[FO[l][1]], c = iv[FO[l][2]];
  cswap(a, b); cswap(a, c); cswap(b, c);
  unsigned long long fk = (unsigned long long)(((long long)a * NVERT + b) * NVERT + c);
  if (p.dmMask){
    unsigned wid = p.dm[hash64(fk) & p.dmMask];
    if (wid == (unsigned)i) return;                  // self-winner: partner links if it exists
    if (wid < (unsigned)(TOLD * 4)){
      int wt = wid >> 2, wl = (int)(wid & 3u);
      int4 wv4 = ((const int4*)p.idxOld)[wt];
      int wv[4] = {wv4.x, wv4.y, wv4.z, wv4.w};
      int wa = wv[FO[wl][0]], wb = wv[FO[wl][1]], wc = wv[FO[wl][2]];
      cswap(wa, wb); cswap(wa, wc); cswap(wb, wc);
      unsigned long long wfk = (unsigned long long)(((long long)wa * NVERT + wb) * NVERT + wc);
      if (wfk == fk){                                // pair found; exactly one linker
        p.nbr[i] = wt;
        p.nbr[wid] = t;
        return;
      }
    }
  }
  face_insert(p.ftab, p.nbr, fk, t, l);              // exact path for collisions
}

// ---- cooperative tail: new_setup -> walk1 -> persist loop -> fallback -> assemble ----

__device__ __forceinline__ void gsync(int* bar){
  __syncthreads();
  if (threadIdx.x == 0){
    __threadfence();                                 // release: L2 writeback
    int gen = __hip_atomic_load(&bar[1], __ATOMIC_RELAXED, __HIP_MEMORY_SCOPE_AGENT);
    int a = __hip_atomic_fetch_add(&bar[0], 1, __ATOMIC_ACQ_REL, __HIP_MEMORY_SCOPE_AGENT);
    if (a == (int)gridDim.x - 1){
      __hip_atomic_store(&bar[0], 0, __ATOMIC_RELAXED, __HIP_MEMORY_SCOPE_AGENT);
      __hip_atomic_store(&bar[1], gen + 1, __ATOMIC_RELEASE, __HIP_MEMORY_SCOPE_AGENT);
    } else {
      while (__hip_atomic_load(&bar[1], __ATOMIC_ACQUIRE, __HIP_MEMORY_SCOPE_AGENT) == gen){
        __builtin_amdgcn_s_sleep(4);
      }
    }
    __threadfence();                                 // acquire: cache invalidate
  }
  __syncthreads();
}

__device__ __forceinline__ bool walk_step(const P& p, int n){
  int c = p.cur[n];
  float4 r0 = p.Tv4[c * 3 + 0];
  float4 r1 = p.Tv4[c * 3 + 1];
  float4 r2 = p.Tv4[c * 3 + 2];
  float4 cn = p.cnew4[n];
  float rx = cn.x - r0.w, ry = cn.y - r1.w, rz = cn.z - r2.w;
  float b0 = r0.x * rx + r0.y * ry + r0.z * rz;
  float b1 = r1.x * rx + r1.y * ry + r1.z * rz;
  float b2 = r2.x * rx + r2.y * ry + r2.z * rz;
  float a0 = 1.0f - (b0 + b1 + b2);
  float ab[4] = {a0, b0, b1, b2};
  int amin = 0; float mn = ab[0];
  for (int j = 1; j < 4; ++j){ if (ab[j] < mn){ mn = ab[j]; amin = j; } }
  if (mn >= -0.0001f){ p.rem[n] = c; return false; }
  int nb = p.degen[c] ? -1 : p.nbr[c * 4 + amin];
  if (nb < 0){ p.rem[n] = c; return false; }
  p.cur[n] = nb;
  return true;
}

__global__ __launch_bounds__(256) void k_coop(P p){
  __shared__ float sd[256];
  __shared__ int si[256];
  int* bar = &p.counters[8];
  const int gtid = blockIdx.x * 256 + threadIdx.x;
  const int gsz = gridDim.x * 256;
  const int n = gtid;

  // ---- phase A: new_setup (per-walker state kept in registers) ----
  int m = 0;
  int4 ni = make_int4(0, 0, 0, 0);
  float nel = 1.0f;
  if (n < TNEW){
    int is64 = detect64(p.rawNew);
    ni.x = ld_idx(p.rawNew, is64, n * 4 + 0);
    ni.y = ld_idx(p.rawNew, is64, n * 4 + 1);
    ni.z = ld_idx(p.rawNew, is64, n * 4 + 2);
    ni.w = ld_idx(p.rawNew, is64, n * 4 + 3);
    int s0 = ni.x, s1 = ni.y, s2 = ni.z, s3 = ni.w;
    cswap(s0, s1); cswap(s2, s3); cswap(s0, s2); cswap(s1, s3); cswap(s1, s2);
    unsigned long long key =
        (unsigned long long)((((long long)s0 * NVERT + s1) * NVERT + s2) * NVERT + s3);
    m = -1;
    unsigned slot = hash64(key) & (THSZ - 1);
    while (true){
      unsigned long long k = p.tkeys[slot];
      if (k == EMPTY64) break;
      if (k == key){ m = p.tvals[slot]; break; }
      slot = (slot + 1) & (THSZ - 1);
    }
    float q0x = p.verts[ni.x * 3 + 0], q0y = p.verts[ni.x * 3 + 1], q0z = p.verts[ni.x * 3 + 2];
    float q1x = p.verts[ni.y * 3 + 0], q1y = p.verts[ni.y * 3 + 1], q1z = p.verts[ni.y * 3 + 2];
    float q2x = p.verts[ni.z * 3 + 0], q2y = p.verts[ni.z * 3 + 1], q2z = p.verts[ni.z * 3 + 2];
    float q3x = p.verts[ni.w * 3 + 0], q3y = p.verts[ni.w * 3 + 1], q3z = p.verts[ni.w * 3 + 2];
    nel = min_edge_r(q0x, q0y, q0z, q1x, q1y, q1z, q2x, q2y, q2z, q3x, q3y, q3z);
    p.cnew4[n] = make_float4((((q0x + q1x) + q2x) + q3x) * 0.25f,
                             (((q0y + q1y) + q2y) + q3y) * 0.25f,
                             (((q0z + q1z) + q2z) + q3z) * 0.25f, nel);
    int pr = p.prio[ni.x];
    int seed = (pr >= 0) ? (pr % TOLD) : 0;
    p.cur[n] = seed;
    p.rem[n] = seed;
    if (m < 0) atomicAdd(&p.counters[0], 1);         // wave-coalesced by compiler
  }
  gsync(bar);

  // ---- phase B: walk body #1 ----
  int nw = p.counters[0];
  if (n < TNEW && m < 0){
    if (nw < 100){                                   // reference loop never runs
      p.listA[atomicAdd(&p.counters[1], 1)] = n;
    } else if (walk_step(p, n)){
      p.listA[atomicAdd(&p.counters[1], 1)] = n;
    }
  }
  gsync(bar);

  // ---- phase C: remaining walk iterations (grid-wide) ----
  int thr = max(100, nw / 1000);
  int use_a = 1, step = 1;
  int count = p.counters[1];
  while (step < MAXSTEPS && count >= thr){
    if (gtid == 0) p.counters[use_a ? 2 : 1] = 0;
    gsync(bar);
    const int* curL = use_a ? p.listA : p.listB;
    int* nxtL = use_a ? p.listB : p.listA;
    int* nxtC = &p.counters[use_a ? 2 : 1];
    for (int i = gtid; i < count; i += gsz){
      int w = curL[i];
      if (walk_step(p, w)) nxtL[atomicAdd(nxtC, 1)] = w;
    }
    gsync(bar);
    use_a ^= 1; ++step;
    count = p.counters[use_a ? 1 : 2];
  }

  // ---- phase D: nearest-centroid fallback for final actives (count < thr) ----
  {
    int fc = count;
    const int* lst = use_a ? p.listA : p.listB;
    for (int e = blockIdx.x; e < fc; e += gridDim.x){
      int wn = lst[e];
      float4 cn = p.cnew4[wn];
      float cx = cn.x, cy = cn.y, cz = cn.z;
      float p2 = (cx * cx + cy * cy) + cz * cz;
      float bd = 3.402823466e+38f; int bi = 0;
      for (int j = threadIdx.x; j < TOLD; j += 256){
        float4 oc = p.cold4[j];
        float dot = (cx * oc.x + cy * oc.y) + cz * oc.z;
        float c2 = (oc.x * oc.x + oc.y * oc.y) + oc.z * oc.z;
        float d = (p2 - 2.0f * dot) + c2;
        if (d < bd || (d == bd && j < bi)){ bd = d; bi = j; }
      }
      sd[threadIdx.x] = bd; si[threadIdx.x] = bi;
      __syncthreads();
      for (int s = 128; s > 0; s >>= 1){
        if ((int)threadIdx.x < s){
          float od = sd[threadIdx.x + s]; int oi = si[threadIdx.x + s];
          if (od < sd[threadIdx.x] || (od == sd[threadIdx.x] && oi < si[threadIdx.x])){
            sd[threadIdx.x] = od; si[threadIdx.x] = oi;
          }
        }
        __syncthreads();
      }
      if (threadIdx.x == 0){
        int r = si[0];
        if (r < 0) r = 0; if (r > TOLD - 1) r = TOLD - 1;
        p.rem[wn] = r;
      }
      __syncthreads();
    }
  }
  gsync(bar);

  // ---- phase E: assemble outputs ----
  if (n < TNEW){
    int remap = (m >= 0) ? m : p.rem[n];
    int cds[5];
    cds[0] = remap;
    int dg = p.degen[remap];
    int4 nb4 = ((const int4*)p.nbr)[remap];
    int nbl[4] = {nb4.x, nb4.y, nb4.z, nb4.w};
    for (int l = 0; l < 4; ++l){
      int fb = dg ? -1 : nbl[l];
      cds[1 + l] = (fb >= 0) ? fb : remap;
    }
    if (m >= 0){ for (int c = 0; c < 5; ++c) cds[c] = m; }
    float nc0 = p.ncc[n * 3 + 0], nc1 = p.ncc[n * 3 + 1], nc2 = p.ncc[n * 3 + 2];
    float raws[5]; float rsum = 0.0f;
    float oels[5];
    for (int c = 0; c < 5; ++c){
      int ct = cds[c];
      int4 cv = ((const int4*)p.idxOld)[ct];
      int ov = 0;
      ov += (cv.x == ni.x || cv.x == ni.y || cv.x == ni.z || cv.x == ni.w) ? 1 : 0;
      ov += (cv.y == ni.x || cv.y == ni.y || cv.y == ni.z || cv.y == ni.w) ? 1 : 0;
      ov += (cv.z == ni.x || cv.z == ni.y || cv.z == ni.z || cv.z == ni.w) ? 1 : 0;
      ov += (cv.w == ni.x || cv.w == ni.y || cv.w == ni.z || cv.w == ni.w) ? 1 : 0;
      float d0 = p.occ[ct * 3 + 0] - nc0;
      float d1 = p.occ[ct * 3 + 1] - nc1;
      float d2 = p.occ[ct * 3 + 2] - nc2;
      float ccd2 = (d0 * d0 + d1 * d1) + d2 * d2;
      float raw = expf((float)ov * 2.0f) / (ccd2 + 1e-8f);
      raws[c] = raw; rsum += raw;
      oels[c] = p.cold4[ct].w;
    }
    float nelv = fmaxf(nel, 1e-8f);
    for (int c = 0; c < 5; ++c){
      p.out[n * 5 + c] = (float)cds[c];
      p.out[TNEW * 5 + n * 5 + c] = raws[c] / rsum;
      float ds = oels[c] / nelv;
      ds = fminf(fmaxf(ds, 0.1f), 10.0f);
      p.out[2 * TNEW * 5 + n * 5 + c] = ds;
    }
  }
}

extern "C" void kernel_launch(void* const* d_in, const int* in_sizes, int n_in,
                              void* d_out, int out_size, void* d_ws, size_t ws_size,
                              hipStream_t stream) {
  char* w = (char*)d_ws;
  P p;
  p.rawNew = (const unsigned int*)d_in[0];
  p.rawOld = (const unsigned int*)d_in[1];
  p.occ    = (const float*)d_in[2];
  p.ncc    = (const float*)d_in[3];
  p.verts  = (const float*)d_in[4];
  p.out    = (float*)d_out;
  p.tkeys    = (unsigned long long*)(w + OFF_TKEYS);
  p.ftab     = (unsigned long long*)(w + OFF_FTAB);
  p.tvals    = (int*)(w + OFF_TVALS);
  p.nbr      = (int*)(w + OFF_NBR);
  p.counters = (int*)(w + OFF_CNT);
  p.prio     = (int*)(w + OFF_PRIO);
  p.idxOld   = (int*)(w + OFF_IDXOLD);
  p.cur      = (int*)(w + OFF_CUR);
  p.rem      = (int*)(w + OFF_REM);
  p.degen    = (int*)(w + OFF_DEGEN);
  p.listA    = (int*)(w + OFF_LISTA);
  p.listB    = (int*)(w + OFF_LISTB);
  p.Tv4      = (float4*)(w + OFF_TV4);
  p.cold4    = (float4*)(w + OFF_COLD4);
  p.cnew4    = (float4*)(w + OFF_CNEW4);
  p.dm       = (unsigned int*)(w + OFF_DM);
  // direct-mapped table size: largest power-of-2 that fits the workspace
  // (constant across calls -> graph-safe). dmMask==0 disables the DM pass.
  size_t avail = (ws_size > (size_t)OFF_DM) ? ws_size - (size_t)OFF_DM : 0;
  unsigned dmMask = 0;
  for (int bshift = 21; bshift >= 16; --bshift){
    if (avail >= ((size_t)4 << bshift)){ dmMask = (1u << bshift) - 1u; break; }
  }
  p.dmMask = dmMask;

  hipMemsetAsync(w, 0xFF, FF_BYTES, stream);
  hipLaunchKernelGGL(k_old_all,      dim3((TOLD + 255) / 256), dim3(256), 0, stream, p);
  hipLaunchKernelGGL(k_prio_resolve, dim3(NWGP + (TOLD * 4 + 255) / 256), dim3(256), 0, stream, p);
  hipLaunchKernelGGL(k_coop,         dim3(NWGC), dim3(256), 0, stream, p);
}

// Round 5
// 255.135 us; speedup vs baseline: 1.1456x; 1.1456x over previous
//
#include <hip/hip_runtime.h>

#pragma clang fp contract(off)

#define TOLD 60000
#define TNEW 60000
#define NVERT 30000
#define MAXSTEPS 300
#define THSZ 131072                  // tet-key hash slots (exact, CAS)
#define FHSZ 131072                  // exact CAS face table (DM-collision fallback only)
#define EMPTY64 0xFFFFFFFFFFFFFFFFULL
#define NWGP 60                      // prio partition WGs (500 verts each)
#define VRANGE 500

// workspace layout: [0xFF-init region][rest, no init needed]
#define OFF_TKEYS    0u              // 131072*8 = 1,048,576
#define OFF_FTAB     1048576u        // 131072*8 = 1,048,576
#define OFF_NBR      2097152u        // 240000*4 =   960,000
#define FF_BYTES     3057152u        // end of 0xFF region
#define OFF_CNT      3057152u        // 256 B (zeroed by k_setup block 0)
#define OFF_TVALS    3057408u        // 524,288 (poison-safe: atomicMax vs negative poison)
#define OFF_PRIO     3581696u        // 120,000 (fully written by k_prio)
#define OFF_IDXOLD   3701696u        // 960,000
#define OFF_CUR      4661696u        // 240,000
#define OFF_REM      4901696u        // 240,000
#define OFF_DEGEN    5141696u        // 240,000
#define OFF_LISTA    5381696u        // 240,000
#define OFF_LISTB    5621696u        // 240,000
#define OFF_MATCHED  5861696u        // 240,000
#define OFF_TV4      6101696u        // 2,880,000 (3 float4/tet: Tinv row + v0 comp)
#define OFF_COLD4    8981696u        // 960,000 (centroid, oel)
#define OFF_CNEW4    9941696u        // 960,000 (centroid, nel)
#define OFF_DM       10901696u       // direct-mapped face table (uninit/poison-safe)

struct P {
  const unsigned int* rawNew;
  const unsigned int* rawOld;
  const float* occ;
  const float* ncc;
  const float* verts;
  float* out;
  unsigned long long* tkeys;
  unsigned long long* ftab;
  int* counters;   // [0]=n_walk/listB cnt [1]=cntA [2]=cntB(pp) [4]=finalCnt [5]=finalList
  int* tvals;
  int* idxOld;
  int* nbr;
  int* prio;
  int* cur; int* rem;
  int* degen;
  int* listA; int* listB;
  int* matched;
  float4* Tv4;
  float4* cold4;
  float4* cnew4;
  unsigned int* dm;
  unsigned int dmMask;               // 0 => DM pass disabled (all faces via exact CAS)
};

__device__ __forceinline__ unsigned hash64(unsigned long long k){
  k ^= k >> 33; k *= 0xff51afd7ed558ccdULL;
  k ^= k >> 33; k *= 0xc4ceb9fe1a85ec53ULL;
  k ^= k >> 33;
  return (unsigned)k;
}
__device__ __forceinline__ void cswap(int& a, int& b){ if (a > b){ int t = a; a = b; b = t; } }

// int64 buffers (values in [0,2^31)) have zero high words at odd u32 positions;
// int32 buffers have col1 >= 1 at flat position 1.
__device__ __forceinline__ int detect64(const unsigned int* raw){
  unsigned acc = 0;
  const uint4* r4 = (const uint4*)raw;
  #pragma unroll
  for (int k = 0; k < 32; ++k){ uint4 v = r4[k]; acc |= (v.y | v.w); }
  return acc == 0u;
}
__device__ __forceinline__ int ld_idx(const unsigned int* raw, int is64, int i){
  return is64 ? (int)((const long long*)raw)[i] : ((const int*)raw)[i];
}

// Exact open-addressing face insert (fallback for DM collisions only).
__device__ __forceinline__ void face_insert(unsigned long long* ftab, int* nbr,
                                            unsigned long long fkey, int t, int l){
  unsigned long long mine = (fkey << 18) | (unsigned long long)(t * 4 + l);
  unsigned slot = hash64(fkey ^ 0x9e3779b97f4a7c15ULL) & (FHSZ - 1);
  while (true){
    unsigned long long prev = atomicCAS(&ftab[slot], EMPTY64, mine);
    if (prev == EMPTY64) return;
    if ((prev >> 18) == fkey){
      int oid = (int)(prev & 0x3FFFFULL);
      nbr[t * 4 + l] = oid >> 2;
      nbr[oid] = t;
      return;
    }
    slot = (slot + 1) & (FHSZ - 1);
  }
}

// min edge length; fold order matches the reference EDGES list exactly.
__device__ __forceinline__ float min_edge_r(
    float q0x, float q0y, float q0z, float q1x, float q1y, float q1z,
    float q2x, float q2y, float q2z, float q3x, float q3y, float q3z){
  float m = 3.402823466e+38f;
  float dx, dy, dz, d;
  dx = q0x - q1x; dy = q0y - q1y; dz = q0z - q1z; d = sqrtf((dx*dx + dy*dy) + dz*dz); m = fminf(m, d);
  dx = q0x - q2x; dy = q0y - q2y; dz = q0z - q2z; d = sqrtf((dx*dx + dy*dy) + dz*dz); m = fminf(m, d);
  dx = q0x - q3x; dy = q0y - q3y; dz = q0z - q3z; d = sqrtf((dx*dx + dy*dy) + dz*dz); m = fminf(m, d);
  dx = q1x - q2x; dy = q1y - q2y; dz = q1z - q2z; d = sqrtf((dx*dx + dy*dy) + dz*dz); m = fminf(m, d);
  dx = q1x - q3x; dy = q1y - q3y; dz = q1z - q3z; d = sqrtf((dx*dx + dy*dy) + dz*dz); m = fminf(m, d);
  dx = q2x - q3x; dy = q2y - q3y; dz = q2z - q3z; d = sqrtf((dx*dx + dy*dy) + dz*dz); m = fminf(m, d);
  return m;
}

// Old-tet pass: idx normalize, geometry, tet-key CAS + value atomicMax,
// direct-mapped face id plain-writes (racy last-wins; resolved in k_face).
// Fabric atomics: ~2 per tet (vs ~10 in the round-2 version).
__global__ __launch_bounds__(256) void k_setup(P p){
  int t = blockIdx.x * blockDim.x + threadIdx.x;
  if (blockIdx.x == 0 && threadIdx.x < 64) p.counters[threadIdx.x] = 0;
  if (t >= TOLD) return;
  int is64 = detect64(p.rawOld);
  int i0 = ld_idx(p.rawOld, is64, t * 4 + 0);
  int i1 = ld_idx(p.rawOld, is64, t * 4 + 1);
  int i2 = ld_idx(p.rawOld, is64, t * 4 + 2);
  int i3 = ld_idx(p.rawOld, is64, t * 4 + 3);
  ((int4*)p.idxOld)[t] = make_int4(i0, i1, i2, i3);

  // tet key insert; duplicate keys keep MAX tet id (exact: atomicMax always).
  // tvals needs no init: 0xAA poison is a large negative int, always loses.
  {
    int s0 = i0, s1 = i1, s2 = i2, s3 = i3;
    cswap(s0, s1); cswap(s2, s3); cswap(s0, s2); cswap(s1, s3); cswap(s1, s2);
    unsigned long long key =
        (unsigned long long)((((long long)s0 * NVERT + s1) * NVERT + s2) * NVERT + s3);
    unsigned slot = hash64(key) & (THSZ - 1);
    while (true){
      unsigned long long prev = atomicCAS(&p.tkeys[slot], EMPTY64, key);
      if (prev == EMPTY64 || prev == key){ atomicMax(&p.tvals[slot], t); break; }
      slot = (slot + 1) & (THSZ - 1);
    }
  }

  // direct-mapped face id writes (plain stores; poison-safe on read side)
  if (p.dmMask){
    const int FO[4][3] = {{1, 2, 3}, {0, 2, 3}, {0, 1, 3}, {0, 1, 2}};
    int iv[4] = {i0, i1, i2, i3};
    #pragma unroll
    for (int l = 0; l < 4; ++l){
      int a = iv[FO[l][0]], b = iv[FO[l][1]], c = iv[FO[l][2]];
      cswap(a, b); cswap(a, c); cswap(b, c);
      unsigned long long fk = (unsigned long long)(((long long)a * NVERT + b) * NVERT + c);
      p.dm[hash64(fk) & p.dmMask] = (unsigned)(t * 4 + l);
    }
  }

  // geometry: Tinv (adjugate/det), v0, centroid, min edge length
  float q0x = p.verts[i0 * 3 + 0], q0y = p.verts[i0 * 3 + 1], q0z = p.verts[i0 * 3 + 2];
  float q1x = p.verts[i1 * 3 + 0], q1y = p.verts[i1 * 3 + 1], q1z = p.verts[i1 * 3 + 2];
  float q2x = p.verts[i2 * 3 + 0], q2y = p.verts[i2 * 3 + 1], q2z = p.verts[i2 * 3 + 2];
  float q3x = p.verts[i3 * 3 + 0], q3y = p.verts[i3 * 3 + 1], q3z = p.verts[i3 * 3 + 2];
  float e1x = q1x - q0x, e1y = q1y - q0y, e1z = q1z - q0z;
  float e2x = q2x - q0x, e2y = q2y - q0y, e2z = q2z - q0z;
  float e3x = q3x - q0x, e3y = q3y - q0y, e3z = q3z - q0z;
  float c23x = e2y * e3z - e2z * e3y;
  float c23y = e2z * e3x - e2x * e3z;
  float c23z = e2x * e3y - e2y * e3x;
  float det = e1x * c23x + e1y * c23y + e1z * c23z;
  int dg = (fabsf(det) < 1e-10f) ? 1 : 0;
  p.degen[t] = dg;
  float4 r0, r1, r2;
  if (dg){
    r0 = make_float4(1.f, 0.f, 0.f, q0x);
    r1 = make_float4(0.f, 1.f, 0.f, q0y);
    r2 = make_float4(0.f, 0.f, 1.f, q0z);
  } else {
    float inv = 1.0f / det;
    float c31x = e3y * e1z - e3z * e1y;
    float c31y = e3z * e1x - e3x * e1z;
    float c31z = e3x * e1y - e3y * e1x;
    float c12x = e1y * e2z - e1z * e2y;
    float c12y = e1z * e2x - e1x * e2z;
    float c12z = e1x * e2y - e1y * e2x;
    r0 = make_float4(c23x * inv, c23y * inv, c23z * inv, q0x);
    r1 = make_float4(c31x * inv, c31y * inv, c31z * inv, q0y);
    r2 = make_float4(c12x * inv, c12y * inv, c12z * inv, q0z);
  }
  p.Tv4[t * 3 + 0] = r0;
  p.Tv4[t * 3 + 1] = r1;
  p.Tv4[t * 3 + 2] = r2;
  float el = min_edge_r(q0x, q0y, q0z, q1x, q1y, q1z, q2x, q2y, q2z, q3x, q3y, q3z);
  p.cold4[t] = make_float4((((q0x + q1x) + q2x) + q3x) * 0.25f,
                           (((q0y + q1y) + q2y) + q3y) * 0.25f,
                           (((q0z + q1z) + q2z) + q3z) * 0.25f, el);
}

// prio via LDS-max partition scan: WG b owns vertices [b*500,(b+1)*500);
// zero fabric atomics, fully writes prio[]. Exact max semantics.
__global__ __launch_bounds__(256) void k_prio(P p){
  __shared__ int sprio[VRANGE];
  int base = blockIdx.x * VRANGE;
  for (int j = threadIdx.x; j < VRANGE; j += 256) sprio[j] = -1;
  __syncthreads();
  int is64 = detect64(p.rawOld);
  for (int t = threadIdx.x; t < TOLD; t += 256){
    int v;
    v = ld_idx(p.rawOld, is64, t * 4 + 0) - base; if ((unsigned)v < VRANGE) atomicMax(&sprio[v], 0 * TOLD + t);
    v = ld_idx(p.rawOld, is64, t * 4 + 1) - base; if ((unsigned)v < VRANGE) atomicMax(&sprio[v], 1 * TOLD + t);
    v = ld_idx(p.rawOld, is64, t * 4 + 2) - base; if ((unsigned)v < VRANGE) atomicMax(&sprio[v], 2 * TOLD + t);
    v = ld_idx(p.rawOld, is64, t * 4 + 3) - base; if ((unsigned)v < VRANGE) atomicMax(&sprio[v], 3 * TOLD + t);
  }
  __syncthreads();
  for (int j = threadIdx.x; j < VRANGE; j += 256) p.prio[base + j] = sprio[j];
}

// Face resolve: one thread per (tet, local face). Both members of a face pair
// read the SAME stable DM slot, so path choice is always symmetric -> exact.
__global__ __launch_bounds__(256) void k_face(P p){
  int i = blockIdx.x * blockDim.x + threadIdx.x;
  if (i >= TOLD * 4) return;
  int t = i >> 2, l = i & 3;
  int4 iv4 = ((const int4*)p.idxOld)[t];
  int iv[4] = {iv4.x, iv4.y, iv4.z, iv4.w};
  const int FO[4][3] = {{1, 2, 3}, {0, 2, 3}, {0, 1, 3}, {0, 1, 2}};
  int a = iv[FO[l][0]], b = iv[FO[l][1]], c = iv[FO[l][2]];
  cswap(a, b); cswap(a, c); cswap(b, c);
  unsigned long long fk = (unsigned long long)(((long long)a * NVERT + b) * NVERT + c);
  if (p.dmMask){
    unsigned wid = p.dm[hash64(fk) & p.dmMask];
    if (wid == (unsigned)i) return;                  // self-winner; partner links if real
    if (wid < (unsigned)(TOLD * 4)){
      int wt = wid >> 2, wl = (int)(wid & 3u);
      int4 wv4 = ((const int4*)p.idxOld)[wt];
      int wv[4] = {wv4.x, wv4.y, wv4.z, wv4.w};
      int wa = wv[FO[wl][0]], wb = wv[FO[wl][1]], wc = wv[FO[wl][2]];
      cswap(wa, wb); cswap(wa, wc); cswap(wb, wc);
      unsigned long long wfk = (unsigned long long)(((long long)wa * NVERT + wb) * NVERT + wc);
      if (wfk == fk){                                // pair found; plain mutual link
        p.nbr[i] = wt;
        p.nbr[wid] = t;
        return;
      }
    }
  }
  face_insert(p.ftab, p.nbr, fk, t, l);              // exact path for DM collisions
}

__device__ __forceinline__ bool walk_step(const P& p, int n){
  int c = p.cur[n];
  float4 r0 = p.Tv4[c * 3 + 0];
  float4 r1 = p.Tv4[c * 3 + 1];
  float4 r2 = p.Tv4[c * 3 + 2];
  float4 cn = p.cnew4[n];
  float rx = cn.x - r0.w, ry = cn.y - r1.w, rz = cn.z - r2.w;
  float b0 = r0.x * rx + r0.y * ry + r0.z * rz;
  float b1 = r1.x * rx + r1.y * ry + r1.z * rz;
  float b2 = r2.x * rx + r2.y * ry + r2.z * rz;
  float a0 = 1.0f - (b0 + b1 + b2);
  float ab[4] = {a0, b0, b1, b2};
  int amin = 0; float mn = ab[0];
  for (int j = 1; j < 4; ++j){ if (ab[j] < mn){ mn = ab[j]; amin = j; } }
  if (mn >= -0.0001f){ p.rem[n] = c; return false; }
  int nb = p.degen[c] ? -1 : p.nbr[c * 4 + amin];
  if (nb < 0){ p.rem[n] = c; return false; }
  p.cur[n] = nb;
  return true;
}

// new_setup + SPECULATIVE walk body #1 (no global n_walk needed):
// if nw turns out < 100, the reference ran no steps, but then fallback
// overrides rem for every unmatched walker, so the speculative writes are
// dead. listB = all unmatched (used iff nw<100), listA = step-1 survivors.
__global__ __launch_bounds__(256) void k_new(P p){
  int n = blockIdx.x * blockDim.x + threadIdx.x;
  if (n >= TNEW) return;
  int is64 = detect64(p.rawNew);
  int i0 = ld_idx(p.rawNew, is64, n * 4 + 0);
  int i1 = ld_idx(p.rawNew, is64, n * 4 + 1);
  int i2 = ld_idx(p.rawNew, is64, n * 4 + 2);
  int i3 = ld_idx(p.rawNew, is64, n * 4 + 3);
  int s0 = i0, s1 = i1, s2 = i2, s3 = i3;
  cswap(s0, s1); cswap(s2, s3); cswap(s0, s2); cswap(s1, s3); cswap(s1, s2);
  unsigned long long key =
      (unsigned long long)((((long long)s0 * NVERT + s1) * NVERT + s2) * NVERT + s3);
  int m = -1;
  {
    unsigned slot = hash64(key) & (THSZ - 1);
    while (true){
      unsigned long long k = p.tkeys[slot];
      if (k == EMPTY64) break;
      if (k == key){ m = p.tvals[slot]; break; }
      slot = (slot + 1) & (THSZ - 1);
    }
  }
  p.matched[n] = m;
  float q0x = p.verts[i0 * 3 + 0], q0y = p.verts[i0 * 3 + 1], q0z = p.verts[i0 * 3 + 2];
  float q1x = p.verts[i1 * 3 + 0], q1y = p.verts[i1 * 3 + 1], q1z = p.verts[i1 * 3 + 2];
  float q2x = p.verts[i2 * 3 + 0], q2y = p.verts[i2 * 3 + 1], q2z = p.verts[i2 * 3 + 2];
  float q3x = p.verts[i3 * 3 + 0], q3y = p.verts[i3 * 3 + 1], q3z = p.verts[i3 * 3 + 2];
  float el = min_edge_r(q0x, q0y, q0z, q1x, q1y, q1z, q2x, q2y, q2z, q3x, q3y, q3z);
  p.cnew4[n] = make_float4((((q0x + q1x) + q2x) + q3x) * 0.25f,
                           (((q0y + q1y) + q2y) + q3y) * 0.25f,
                           (((q0z + q1z) + q2z) + q3z) * 0.25f, el);
  if (m >= 0) return;
  int pr = p.prio[i0];
  int seed = (pr >= 0) ? (pr % TOLD) : 0;
  p.cur[n] = seed;
  p.rem[n] = seed;
  p.listB[atomicAdd(&p.counters[0], 1)] = n;         // all-unmatched list (nw<100 path)
  if (walk_step(p, n))
    p.listA[atomicAdd(&p.counters[1], 1)] = n;       // step-1 survivors (nw>=100 path)
}

__global__ void __launch_bounds__(1024) k_persist(P p){
  __shared__ int s_cnt;
  int nw = p.counters[0];
  if (nw < 100){
    // reference while-loop never ran; every unmatched walker goes to fallback
    if (threadIdx.x == 0){ p.counters[4] = nw; p.counters[5] = 1; }
    return;
  }
  int thr = max(100, nw / 1000);
  if (threadIdx.x == 0) s_cnt = atomicAdd(&p.counters[1], 0);
  __syncthreads();
  int count = s_cnt;
  int use_a = 1;
  int step = 1;                        // k_new performed body #1
  while (step < MAXSTEPS && count >= thr){
    int* curL = use_a ? p.listA : p.listB;
    int* nxtL = use_a ? p.listB : p.listA;
    int* nxtC = use_a ? &p.counters[2] : &p.counters[1];
    int* curC = use_a ? &p.counters[1] : &p.counters[2];
    for (int i = threadIdx.x; i < count; i += blockDim.x){
      int n = curL[i];
      if (walk_step(p, n)){
        int pos = atomicAdd(nxtC, 1);
        nxtL[pos] = n;
      }
    }
    __syncthreads();
    if (threadIdx.x == 0){
      s_cnt = atomicAdd(nxtC, 0);
      atomicExch(curC, 0);
    }
    __syncthreads();
    count = s_cnt;
    use_a ^= 1;
    ++step;
  }
  if (threadIdx.x == 0){
    p.counters[4] = count;
    p.counters[5] = use_a ? 0 : 1;     // 0=listA holds final actives, 1=listB
  }
}

// Nearest-old-centroid fallback for final actives only. Reference tie-break
// == first index achieving the global float min.
__global__ __launch_bounds__(256) void k_fallback(P p){
  __shared__ float sd[256];
  __shared__ int si[256];
  int fc = p.counters[4];
  const int* lst = p.counters[5] ? p.listB : p.listA;
  for (int e = blockIdx.x; e < fc; e += gridDim.x){
    int n = lst[e];
    float4 cn = p.cnew4[n];
    float cx = cn.x, cy = cn.y, cz = cn.z;
    float p2 = (cx * cx + cy * cy) + cz * cz;
    float bd = 3.402823466e+38f; int bi = 0;
    for (int j = threadIdx.x; j < TOLD; j += 256){
      float4 oc = p.cold4[j];
      float dot = (cx * oc.x + cy * oc.y) + cz * oc.z;
      float c2 = (oc.x * oc.x + oc.y * oc.y) + oc.z * oc.z;
      float d = (p2 - 2.0f * dot) + c2;
      if (d < bd || (d == bd && j < bi)){ bd = d; bi = j; }
    }
    sd[threadIdx.x] = bd; si[threadIdx.x] = bi;
    __syncthreads();
    for (int s = 128; s > 0; s >>= 1){
      if ((int)threadIdx.x < s){
        float od = sd[threadIdx.x + s]; int oi = si[threadIdx.x + s];
        if (od < sd[threadIdx.x] || (od == sd[threadIdx.x] && oi < si[threadIdx.x])){
          sd[threadIdx.x] = od; si[threadIdx.x] = oi;
        }
      }
      __syncthreads();
    }
    if (threadIdx.x == 0){
      int r = si[0];
      if (r < 0) r = 0; if (r > TOLD - 1) r = TOLD - 1;
      p.rem[n] = r;
    }
    __syncthreads();
  }
}

__global__ __launch_bounds__(256) void k_assemble(P p){
  int n = blockIdx.x * blockDim.x + threadIdx.x;
  if (n >= TNEW) return;
  int m = p.matched[n];
  int remap = (m >= 0) ? m : p.rem[n];
  int cds[5];
  cds[0] = remap;
  int dg = p.degen[remap];
  int4 nb4 = ((const int4*)p.nbr)[remap];
  int nbl[4] = {nb4.x, nb4.y, nb4.z, nb4.w};
  for (int l = 0; l < 4; ++l){
    int fb = dg ? -1 : nbl[l];
    cds[1 + l] = (fb >= 0) ? fb : remap;
  }
  if (m >= 0){ for (int c = 0; c < 5; ++c) cds[c] = m; }
  int is64 = detect64(p.rawNew);
  int nix = ld_idx(p.rawNew, is64, n * 4 + 0);
  int niy = ld_idx(p.rawNew, is64, n * 4 + 1);
  int niz = ld_idx(p.rawNew, is64, n * 4 + 2);
  int niw = ld_idx(p.rawNew, is64, n * 4 + 3);
  float nc0 = p.ncc[n * 3 + 0], nc1 = p.ncc[n * 3 + 1], nc2 = p.ncc[n * 3 + 2];
  float raws[5]; float rsum = 0.0f;
  float oels[5];
  for (int c = 0; c < 5; ++c){
    int ct = cds[c];
    int4 cv = ((const int4*)p.idxOld)[ct];
    int ov = 0;
    ov += (cv.x == nix || cv.x == niy || cv.x == niz || cv.x == niw) ? 1 : 0;
    ov += (cv.y == nix || cv.y == niy || cv.y == niz || cv.y == niw) ? 1 : 0;
    ov += (cv.z == nix || cv.z == niy || cv.z == niz || cv.z == niw) ? 1 : 0;
    ov += (cv.w == nix || cv.w == niy || cv.w == niz || cv.w == niw) ? 1 : 0;
    float d0 = p.occ[ct * 3 + 0] - nc0;
    float d1 = p.occ[ct * 3 + 1] - nc1;
    float d2 = p.occ[ct * 3 + 2] - nc2;
    float ccd2 = (d0 * d0 + d1 * d1) + d2 * d2;
    float raw = expf((float)ov * 2.0f) / (ccd2 + 1e-8f);
    raws[c] = raw; rsum += raw;
    oels[c] = p.cold4[ct].w;
  }
  float nelv = fmaxf(p.cnew4[n].w, 1e-8f);
  for (int c = 0; c < 5; ++c){
    p.out[n * 5 + c] = (float)cds[c];
    p.out[TNEW * 5 + n * 5 + c] = raws[c] / rsum;
    float ds = oels[c] / nelv;
    ds = fminf(fmaxf(ds, 0.1f), 10.0f);
    p.out[2 * TNEW * 5 + n * 5 + c] = ds;
  }
}

extern "C" void kernel_launch(void* const* d_in, const int* in_sizes, int n_in,
                              void* d_out, int out_size, void* d_ws, size_t ws_size,
                              hipStream_t stream) {
  char* w = (char*)d_ws;
  P p;
  p.rawNew = (const unsigned int*)d_in[0];
  p.rawOld = (const unsigned int*)d_in[1];
  p.occ    = (const float*)d_in[2];
  p.ncc    = (const float*)d_in[3];
  p.verts  = (const float*)d_in[4];
  p.out    = (float*)d_out;
  p.tkeys    = (unsigned long long*)(w + OFF_TKEYS);
  p.ftab     = (unsigned long long*)(w + OFF_FTAB);
  p.nbr      = (int*)(w + OFF_NBR);
  p.counters = (int*)(w + OFF_CNT);
  p.tvals    = (int*)(w + OFF_TVALS);
  p.prio     = (int*)(w + OFF_PRIO);
  p.idxOld   = (int*)(w + OFF_IDXOLD);
  p.cur      = (int*)(w + OFF_CUR);
  p.rem      = (int*)(w + OFF_REM);
  p.degen    = (int*)(w + OFF_DEGEN);
  p.listA    = (int*)(w + OFF_LISTA);
  p.listB    = (int*)(w + OFF_LISTB);
  p.matched  = (int*)(w + OFF_MATCHED);
  p.Tv4      = (float4*)(w + OFF_TV4);
  p.cold4    = (float4*)(w + OFF_COLD4);
  p.cnew4    = (float4*)(w + OFF_CNEW4);
  p.dm       = (unsigned int*)(w + OFF_DM);
  size_t avail = (ws_size > (size_t)OFF_DM) ? ws_size - (size_t)OFF_DM : 0;
  unsigned dmMask = 0;
  for (int bshift = 21; bshift >= 16; --bshift){
    if (avail >= ((size_t)4 << bshift)){ dmMask = (1u << bshift) - 1u; break; }
  }
  p.dmMask = dmMask;

  hipMemsetAsync(w, 0xFF, FF_BYTES, stream);
  hipLaunchKernelGGL(k_setup,    dim3((TOLD + 255) / 256), dim3(256), 0, stream, p);
  hipLaunchKernelGGL(k_prio,     dim3(NWGP), dim3(256), 0, stream, p);
  hipLaunchKernelGGL(k_face,     dim3((TOLD * 4 + 255) / 256), dim3(256), 0, stream, p);
  hipLaunchKernelGGL(k_new,      dim3((TNEW + 255) / 256), dim3(256), 0, stream, p);
  hipLaunchKernelGGL(k_persist,  dim3(1), dim3(1024), 0, stream, p);
  hipLaunchKernelGGL(k_fallback, dim3(120), dim3(256), 0, stream, p);
  hipLaunchKernelGGL(k_assemble, dim3((TNEW + 255) / 256), dim3(256), 0, stream, p);
}

// Round 6
// 142.764 us; speedup vs baseline: 2.0474x; 1.7871x over previous
//
#include <hip/hip_runtime.h>

#pragma clang fp contract(off)

#define TOLD 60000
#define TNEW 60000
#define NVERT 30000
#define MAXSTEPS 300
#define THSZ 131072                  // tet-key hash slots (exact, CAS)
#define FHSZ 131072                  // exact CAS face table (DM-collision fallback only)
#define EMPTY64 0xFFFFFFFFFFFFFFFFULL
#define NWGR 60                      // prio vertex ranges (500 verts each)
#define VRANGE 500
#define NSLICE 16                    // prio tet slices
#define TSLICE (TOLD / NSLICE)       // 3750

// workspace layout: [0xFF-init region][rest, no init needed]
#define OFF_TKEYS    0u              // 131072*8 = 1,048,576
#define OFF_FTAB     1048576u        // 131072*8 = 1,048,576
#define OFF_NBR      2097152u        // 240000*4 =   960,000
#define FF_BYTES     3057152u        // end of 0xFF region
#define OFF_CNT      3057152u        // 256 B (zeroed by k_setup block 0)
#define OFF_TVALS    3057408u        // 524,288 (poison-safe: atomicMax vs negative poison)
#define OFF_PPRIO    3581696u        // 16*30000*4 = 1,920,000 (fully written by k_prio2)
#define OFF_IDXOLD   5501696u        // 960,000
#define OFF_CUR      6461696u        // 240,000
#define OFF_REM      6701696u        // 240,000
#define OFF_DEGEN    6941696u        // 240,000
#define OFF_LISTA    7181696u        // 240,000
#define OFF_LISTB    7421696u        // 240,000
#define OFF_MATCHED  7661696u        // 240,000
#define OFF_TV4      7901696u        // 2,880,000 (3 float4/tet: Tinv row + v0 comp)
#define OFF_COLD4    10781696u       // 960,000 (centroid, oel)
#define OFF_CNEW4    11741696u       // 960,000 (centroid, nel)
#define OFF_DM       12701696u       // direct-mapped face table (uninit/poison-safe)

struct P {
  const unsigned int* rawNew;
  const unsigned int* rawOld;
  const float* occ;
  const float* ncc;
  const float* verts;
  float* out;
  unsigned long long* tkeys;
  unsigned long long* ftab;
  int* counters;   // [0]=n_walk/listB cnt [1]=cntA [2]=cntB(pp) [4]=finalCnt [5]=finalList
  int* tvals;
  int* idxOld;
  int* nbr;
  int* pprio;                        // partial prio (NSLICE, NVERT)
  int* cur; int* rem;
  int* degen;
  int* listA; int* listB;
  int* matched;
  float4* Tv4;
  float4* cold4;
  float4* cnew4;
  unsigned int* dm;
  unsigned int dmMask;               // 0 => DM pass disabled (all faces via exact CAS)
};

__device__ __forceinline__ unsigned hash64(unsigned long long k){
  k ^= k >> 33; k *= 0xff51afd7ed558ccdULL;
  k ^= k >> 33; k *= 0xc4ceb9fe1a85ec53ULL;
  k ^= k >> 33;
  return (unsigned)k;
}
__device__ __forceinline__ void cswap(int& a, int& b){ if (a > b){ int t = a; a = b; b = t; } }

// int64 buffers (values in [0,2^31)) have zero high words at odd u32 positions;
// int32 buffers have col1 >= 1 at flat position 1.
__device__ __forceinline__ int detect64(const unsigned int* raw){
  unsigned acc = 0;
  const uint4* r4 = (const uint4*)raw;
  #pragma unroll
  for (int k = 0; k < 32; ++k){ uint4 v = r4[k]; acc |= (v.y | v.w); }
  return acc == 0u;
}

// whole tet record via dwordx4 loads (2 for int64, 1 for int32)
__device__ __forceinline__ int4 load_tet4(const unsigned int* raw, int is64, int t){
  if (is64){
    uint4 a = ((const uint4*)raw)[t * 2 + 0];
    uint4 b = ((const uint4*)raw)[t * 2 + 1];
    return make_int4((int)a.x, (int)a.z, (int)b.x, (int)b.z);
  }
  uint4 a = ((const uint4*)raw)[t];
  return make_int4((int)a.x, (int)a.y, (int)a.z, (int)a.w);
}

// Exact open-addressing face insert (fallback for DM collisions only).
__device__ __forceinline__ void face_insert(unsigned long long* ftab, int* nbr,
                                            unsigned long long fkey, int t, int l){
  unsigned long long mine = (fkey << 18) | (unsigned long long)(t * 4 + l);
  unsigned slot = hash64(fkey ^ 0x9e3779b97f4a7c15ULL) & (FHSZ - 1);
  while (true){
    unsigned long long prev = atomicCAS(&ftab[slot], EMPTY64, mine);
    if (prev == EMPTY64) return;
    if ((prev >> 18) == fkey){
      int oid = (int)(prev & 0x3FFFFULL);
      nbr[t * 4 + l] = oid >> 2;
      nbr[oid] = t;
      return;
    }
    slot = (slot + 1) & (FHSZ - 1);
  }
}

// min edge length; fold order matches the reference EDGES list exactly.
__device__ __forceinline__ float min_edge_r(
    float q0x, float q0y, float q0z, float q1x, float q1y, float q1z,
    float q2x, float q2y, float q2z, float q3x, float q3y, float q3z){
  float m = 3.402823466e+38f;
  float dx, dy, dz, d;
  dx = q0x - q1x; dy = q0y - q1y; dz = q0z - q1z; d = sqrtf((dx*dx + dy*dy) + dz*dz); m = fminf(m, d);
  dx = q0x - q2x; dy = q0y - q2y; dz = q0z - q2z; d = sqrtf((dx*dx + dy*dy) + dz*dz); m = fminf(m, d);
  dx = q0x - q3x; dy = q0y - q3y; dz = q0z - q3z; d = sqrtf((dx*dx + dy*dy) + dz*dz); m = fminf(m, d);
  dx = q1x - q2x; dy = q1y - q2y; dz = q1z - q2z; d = sqrtf((dx*dx + dy*dy) + dz*dz); m = fminf(m, d);
  dx = q1x - q3x; dy = q1y - q3y; dz = q1z - q3z; d = sqrtf((dx*dx + dy*dy) + dz*dz); m = fminf(m, d);
  dx = q2x - q3x; dy = q2y - q3y; dz = q2z - q3z; d = sqrtf((dx*dx + dy*dy) + dz*dz); m = fminf(m, d);
  return m;
}

// Old-tet pass: idx normalize, geometry, tet-key CAS + value atomicMax,
// direct-mapped face id plain-writes (racy last-wins; resolved in k_face).
__global__ __launch_bounds__(256) void k_setup(P p){
  int t = blockIdx.x * blockDim.x + threadIdx.x;
  if (blockIdx.x == 0 && threadIdx.x < 64) p.counters[threadIdx.x] = 0;
  if (t >= TOLD) return;
  int is64 = detect64(p.rawOld);
  int4 iv4 = load_tet4(p.rawOld, is64, t);
  int i0 = iv4.x, i1 = iv4.y, i2 = iv4.z, i3 = iv4.w;
  ((int4*)p.idxOld)[t] = iv4;

  // tet key insert; duplicate keys keep MAX tet id (exact: atomicMax always).
  // tvals needs no init: 0xAA poison is a large negative int, always loses.
  {
    int s0 = i0, s1 = i1, s2 = i2, s3 = i3;
    cswap(s0, s1); cswap(s2, s3); cswap(s0, s2); cswap(s1, s3); cswap(s1, s2);
    unsigned long long key =
        (unsigned long long)((((long long)s0 * NVERT + s1) * NVERT + s2) * NVERT + s3);
    unsigned slot = hash64(key) & (THSZ - 1);
    while (true){
      unsigned long long prev = atomicCAS(&p.tkeys[slot], EMPTY64, key);
      if (prev == EMPTY64 || prev == key){ atomicMax(&p.tvals[slot], t); break; }
      slot = (slot + 1) & (THSZ - 1);
    }
  }

  // direct-mapped face id writes (plain stores; poison-safe on read side)
  if (p.dmMask){
    const int FO[4][3] = {{1, 2, 3}, {0, 2, 3}, {0, 1, 3}, {0, 1, 2}};
    int iv[4] = {i0, i1, i2, i3};
    #pragma unroll
    for (int l = 0; l < 4; ++l){
      int a = iv[FO[l][0]], b = iv[FO[l][1]], c = iv[FO[l][2]];
      cswap(a, b); cswap(a, c); cswap(b, c);
      unsigned long long fk = (unsigned long long)(((long long)a * NVERT + b) * NVERT + c);
      p.dm[hash64(fk) & p.dmMask] = (unsigned)(t * 4 + l);
    }
  }

  // geometry: Tinv (adjugate/det), v0, centroid, min edge length
  float q0x = p.verts[i0 * 3 + 0], q0y = p.verts[i0 * 3 + 1], q0z = p.verts[i0 * 3 + 2];
  float q1x = p.verts[i1 * 3 + 0], q1y = p.verts[i1 * 3 + 1], q1z = p.verts[i1 * 3 + 2];
  float q2x = p.verts[i2 * 3 + 0], q2y = p.verts[i2 * 3 + 1], q2z = p.verts[i2 * 3 + 2];
  float q3x = p.verts[i3 * 3 + 0], q3y = p.verts[i3 * 3 + 1], q3z = p.verts[i3 * 3 + 2];
  float e1x = q1x - q0x, e1y = q1y - q0y, e1z = q1z - q0z;
  float e2x = q2x - q0x, e2y = q2y - q0y, e2z = q2z - q0z;
  float e3x = q3x - q0x, e3y = q3y - q0y, e3z = q3z - q0z;
  float c23x = e2y * e3z - e2z * e3y;
  float c23y = e2z * e3x - e2x * e3z;
  float c23z = e2x * e3y - e2y * e3x;
  float det = e1x * c23x + e1y * c23y + e1z * c23z;
  int dg = (fabsf(det) < 1e-10f) ? 1 : 0;
  p.degen[t] = dg;
  float4 r0, r1, r2;
  if (dg){
    r0 = make_float4(1.f, 0.f, 0.f, q0x);
    r1 = make_float4(0.f, 1.f, 0.f, q0y);
    r2 = make_float4(0.f, 0.f, 1.f, q0z);
  } else {
    float inv = 1.0f / det;
    float c31x = e3y * e1z - e3z * e1y;
    float c31y = e3z * e1x - e3x * e1z;
    float c31z = e3x * e1y - e3y * e1x;
    float c12x = e1y * e2z - e1z * e2y;
    float c12y = e1z * e2x - e1x * e2z;
    float c12z = e1x * e2y - e1y * e2x;
    r0 = make_float4(c23x * inv, c23y * inv, c23z * inv, q0x);
    r1 = make_float4(c31x * inv, c31y * inv, c31z * inv, q0y);
    r2 = make_float4(c12x * inv, c12y * inv, c12z * inv, q0z);
  }
  p.Tv4[t * 3 + 0] = r0;
  p.Tv4[t * 3 + 1] = r1;
  p.Tv4[t * 3 + 2] = r2;
  float el = min_edge_r(q0x, q0y, q0z, q1x, q1y, q1z, q2x, q2y, q2z, q3x, q3y, q3z);
  p.cold4[t] = make_float4((((q0x + q1x) + q2x) + q3x) * 0.25f,
                           (((q0y + q1y) + q2y) + q3y) * 0.25f,
                           (((q0z + q1z) + q2z) + q3z) * 0.25f, el);
}

// prio partial-max: WG (range, slice) LDS-maxes its 3750-tet slice over its
// 500-vertex range, plain-stores pprio[slice][range*500..]. 960 WGs, zero
// fabric atomics, 15 load-iterations per thread. Final 16-way max in k_new.
__global__ __launch_bounds__(256) void k_prio2(P p){
  __shared__ int sprio[VRANGE];
  int range = blockIdx.x / NSLICE;
  int slice = blockIdx.x % NSLICE;
  int base = range * VRANGE;
  for (int j = threadIdx.x; j < VRANGE; j += 256) sprio[j] = -1;
  __syncthreads();
  int is64 = detect64(p.rawOld);
  int t0 = slice * TSLICE;
  for (int t = t0 + threadIdx.x; t < t0 + TSLICE; t += 256){
    int4 iv = load_tet4(p.rawOld, is64, t);
    int v;
    v = iv.x - base; if ((unsigned)v < VRANGE) atomicMax(&sprio[v], 0 * TOLD + t);
    v = iv.y - base; if ((unsigned)v < VRANGE) atomicMax(&sprio[v], 1 * TOLD + t);
    v = iv.z - base; if ((unsigned)v < VRANGE) atomicMax(&sprio[v], 2 * TOLD + t);
    v = iv.w - base; if ((unsigned)v < VRANGE) atomicMax(&sprio[v], 3 * TOLD + t);
  }
  __syncthreads();
  for (int j = threadIdx.x; j < VRANGE; j += 256)
    p.pprio[slice * NVERT + base + j] = sprio[j];
}

// Face resolve: one thread per (tet, local face). Both members of a face pair
// read the SAME stable DM slot, so path choice is always symmetric -> exact.
__global__ __launch_bounds__(256) void k_face(P p){
  int i = blockIdx.x * blockDim.x + threadIdx.x;
  if (i >= TOLD * 4) return;
  int t = i >> 2, l = i & 3;
  int4 iv4 = ((const int4*)p.idxOld)[t];
  int iv[4] = {iv4.x, iv4.y, iv4.z, iv4.w};
  const int FO[4][3] = {{1, 2, 3}, {0, 2, 3}, {0, 1, 3}, {0, 1, 2}};
  int a = iv[FO[l][0]], b = iv[FO[l][1]], c = iv[FO[l][2]];
  cswap(a, b); cswap(a, c); cswap(b, c);
  unsigned long long fk = (unsigned long long)(((long long)a * NVERT + b) * NVERT + c);
  if (p.dmMask){
    unsigned wid = p.dm[hash64(fk) & p.dmMask];
    if (wid == (unsigned)i) return;                  // self-winner; partner links if real
    if (wid < (unsigned)(TOLD * 4)){
      int wt = wid >> 2, wl = (int)(wid & 3u);
      int4 wv4 = ((const int4*)p.idxOld)[wt];
      int wv[4] = {wv4.x, wv4.y, wv4.z, wv4.w};
      int wa = wv[FO[wl][0]], wb = wv[FO[wl][1]], wc = wv[FO[wl][2]];
      cswap(wa, wb); cswap(wa, wc); cswap(wb, wc);
      unsigned long long wfk = (unsigned long long)(((long long)wa * NVERT + wb) * NVERT + wc);
      if (wfk == fk){                                // pair found; plain mutual link
        p.nbr[i] = wt;
        p.nbr[wid] = t;
        return;
      }
    }
  }
  face_insert(p.ftab, p.nbr, fk, t, l);              // exact path for DM collisions
}

__device__ __forceinline__ bool walk_step(const P& p, int n){
  int c = p.cur[n];
  float4 r0 = p.Tv4[c * 3 + 0];
  float4 r1 = p.Tv4[c * 3 + 1];
  float4 r2 = p.Tv4[c * 3 + 2];
  float4 cn = p.cnew4[n];
  float rx = cn.x - r0.w, ry = cn.y - r1.w, rz = cn.z - r2.w;
  float b0 = r0.x * rx + r0.y * ry + r0.z * rz;
  float b1 = r1.x * rx + r1.y * ry + r1.z * rz;
  float b2 = r2.x * rx + r2.y * ry + r2.z * rz;
  float a0 = 1.0f - (b0 + b1 + b2);
  float ab[4] = {a0, b0, b1, b2};
  int amin = 0; float mn = ab[0];
  for (int j = 1; j < 4; ++j){ if (ab[j] < mn){ mn = ab[j]; amin = j; } }
  if (mn >= -0.0001f){ p.rem[n] = c; return false; }
  int nb = p.degen[c] ? -1 : p.nbr[c * 4 + amin];
  if (nb < 0){ p.rem[n] = c; return false; }
  p.cur[n] = nb;
  return true;
}

// new_setup + SPECULATIVE walk body #1: if n_walk turns out < 100 the
// reference ran no steps, but then fallback overrides rem for every unmatched
// walker, so the speculative writes are dead. listB = all unmatched (nw<100
// path), listA = step-1 survivors (nw>=100 path).
__global__ __launch_bounds__(256) void k_new(P p){
  int n = blockIdx.x * blockDim.x + threadIdx.x;
  if (n >= TNEW) return;
  int is64 = detect64(p.rawNew);
  int4 ni = load_tet4(p.rawNew, is64, n);
  int i0 = ni.x, i1 = ni.y, i2 = ni.z, i3 = ni.w;
  int s0 = i0, s1 = i1, s2 = i2, s3 = i3;
  cswap(s0, s1); cswap(s2, s3); cswap(s0, s2); cswap(s1, s3); cswap(s1, s2);
  unsigned long long key =
      (unsigned long long)((((long long)s0 * NVERT + s1) * NVERT + s2) * NVERT + s3);
  int m = -1;
  {
    unsigned slot = hash64(key) & (THSZ - 1);
    while (true){
      unsigned long long k = p.tkeys[slot];
      if (k == EMPTY64) break;
      if (k == key){ m = p.tvals[slot]; break; }
      slot = (slot + 1) & (THSZ - 1);
    }
  }
  p.matched[n] = m;
  float q0x = p.verts[i0 * 3 + 0], q0y = p.verts[i0 * 3 + 1], q0z = p.verts[i0 * 3 + 2];
  float q1x = p.verts[i1 * 3 + 0], q1y = p.verts[i1 * 3 + 1], q1z = p.verts[i1 * 3 + 2];
  float q2x = p.verts[i2 * 3 + 0], q2y = p.verts[i2 * 3 + 1], q2z = p.verts[i2 * 3 + 2];
  float q3x = p.verts[i3 * 3 + 0], q3y = p.verts[i3 * 3 + 1], q3z = p.verts[i3 * 3 + 2];
  float el = min_edge_r(q0x, q0y, q0z, q1x, q1y, q1z, q2x, q2y, q2z, q3x, q3y, q3z);
  p.cnew4[n] = make_float4((((q0x + q1x) + q2x) + q3x) * 0.25f,
                           (((q0y + q1y) + q2y) + q3y) * 0.25f,
                           (((q0z + q1z) + q2z) + q3z) * 0.25f, el);
  if (m >= 0) return;
  // folded 16-way partial-prio reduce (exact max)
  int pr = -1;
  #pragma unroll
  for (int s = 0; s < NSLICE; ++s) pr = max(pr, p.pprio[s * NVERT + i0]);
  int seed = (pr >= 0) ? (pr % TOLD) : 0;
  p.cur[n] = seed;
  p.rem[n] = seed;
  p.listB[atomicAdd(&p.counters[0], 1)] = n;         // all-unmatched list (nw<100 path)
  if (walk_step(p, n))
    p.listA[atomicAdd(&p.counters[1], 1)] = n;       // step-1 survivors (nw>=100 path)
}

__global__ void __launch_bounds__(1024) k_persist(P p){
  __shared__ int s_cnt;
  int nw = p.counters[0];
  if (nw < 100){
    // reference while-loop never ran; every unmatched walker goes to fallback
    if (threadIdx.x == 0){ p.counters[4] = nw; p.counters[5] = 1; }
    return;
  }
  int thr = max(100, nw / 1000);
  if (threadIdx.x == 0) s_cnt = atomicAdd(&p.counters[1], 0);
  __syncthreads();
  int count = s_cnt;
  int use_a = 1;
  int step = 1;                        // k_new performed body #1
  while (step < MAXSTEPS && count >= thr){
    int* curL = use_a ? p.listA : p.listB;
    int* nxtL = use_a ? p.listB : p.listA;
    int* nxtC = use_a ? &p.counters[2] : &p.counters[1];
    int* curC = use_a ? &p.counters[1] : &p.counters[2];
    for (int i = threadIdx.x; i < count; i += blockDim.x){
      int n = curL[i];
      if (walk_step(p, n)){
        int pos = atomicAdd(nxtC, 1);
        nxtL[pos] = n;
      }
    }
    __syncthreads();
    if (threadIdx.x == 0){
      s_cnt = atomicAdd(nxtC, 0);
      atomicExch(curC, 0);
    }
    __syncthreads();
    count = s_cnt;
    use_a ^= 1;
    ++step;
  }
  if (threadIdx.x == 0){
    p.counters[4] = count;
    p.counters[5] = use_a ? 0 : 1;     // 0=listA holds final actives, 1=listB
  }
}

// Nearest-old-centroid fallback for final actives only. Reference tie-break
// == first index achieving the global float min.
__global__ __launch_bounds__(256) void k_fallback(P p){
  __shared__ float sd[256];
  __shared__ int si[256];
  int fc = p.counters[4];
  const int* lst = p.counters[5] ? p.listB : p.listA;
  for (int e = blockIdx.x; e < fc; e += gridDim.x){
    int n = lst[e];
    float4 cn = p.cnew4[n];
    float cx = cn.x, cy = cn.y, cz = cn.z;
    float p2 = (cx * cx + cy * cy) + cz * cz;
    float bd = 3.402823466e+38f; int bi = 0;
    for (int j = threadIdx.x; j < TOLD; j += 256){
      float4 oc = p.cold4[j];
      float dot = (cx * oc.x + cy * oc.y) + cz * oc.z;
      float c2 = (oc.x * oc.x + oc.y * oc.y) + oc.z * oc.z;
      float d = (p2 - 2.0f * dot) + c2;
      if (d < bd || (d == bd && j < bi)){ bd = d; bi = j; }
    }
    sd[threadIdx.x] = bd; si[threadIdx.x] = bi;
    __syncthreads();
    for (int s = 128; s > 0; s >>= 1){
      if ((int)threadIdx.x < s){
        float od = sd[threadIdx.x + s]; int oi = si[threadIdx.x + s];
        if (od < sd[threadIdx.x] || (od == sd[threadIdx.x] && oi < si[threadIdx.x])){
          sd[threadIdx.x] = od; si[threadIdx.x] = oi;
        }
      }
      __syncthreads();
    }
    if (threadIdx.x == 0){
      int r = si[0];
      if (r < 0) r = 0; if (r > TOLD - 1) r = TOLD - 1;
      p.rem[n] = r;
    }
    __syncthreads();
  }
}

__global__ __launch_bounds__(256) void k_assemble(P p){
  int n = blockIdx.x * blockDim.x + threadIdx.x;
  if (n >= TNEW) return;
  int m = p.matched[n];
  int remap = (m >= 0) ? m : p.rem[n];
  int cds[5];
  cds[0] = remap;
  int dg = p.degen[remap];
  int4 nb4 = ((const int4*)p.nbr)[remap];
  int nbl[4] = {nb4.x, nb4.y, nb4.z, nb4.w};
  for (int l = 0; l < 4; ++l){
    int fb = dg ? -1 : nbl[l];
    cds[1 + l] = (fb >= 0) ? fb : remap;
  }
  if (m >= 0){ for (int c = 0; c < 5; ++c) cds[c] = m; }
  int is64 = detect64(p.rawNew);
  int4 ni = load_tet4(p.rawNew, is64, n);
  float nc0 = p.ncc[n * 3 + 0], nc1 = p.ncc[n * 3 + 1], nc2 = p.ncc[n * 3 + 2];
  float raws[5]; float rsum = 0.0f;
  float oels[5];
  for (int c = 0; c < 5; ++c){
    int ct = cds[c];
    int4 cv = ((const int4*)p.idxOld)[ct];
    int ov = 0;
    ov += (cv.x == ni.x || cv.x == ni.y || cv.x == ni.z || cv.x == ni.w) ? 1 : 0;
    ov += (cv.y == ni.x || cv.y == ni.y || cv.y == ni.z || cv.y == ni.w) ? 1 : 0;
    ov += (cv.z == ni.x || cv.z == ni.y || cv.z == ni.z || cv.z == ni.w) ? 1 : 0;
    ov += (cv.w == ni.x || cv.w == ni.y || cv.w == ni.z || cv.w == ni.w) ? 1 : 0;
    float d0 = p.occ[ct * 3 + 0] - nc0;
    float d1 = p.occ[ct * 3 + 1] - nc1;
    float d2 = p.occ[ct * 3 + 2] - nc2;
    float ccd2 = (d0 * d0 + d1 * d1) + d2 * d2;
    float raw = expf((float)ov * 2.0f) / (ccd2 + 1e-8f);
    raws[c] = raw; rsum += raw;
    oels[c] = p.cold4[ct].w;
  }
  float nelv = fmaxf(p.cnew4[n].w, 1e-8f);
  for (int c = 0; c < 5; ++c){
    p.out[n * 5 + c] = (float)cds[c];
    p.out[TNEW * 5 + n * 5 + c] = raws[c] / rsum;
    float ds = oels[c] / nelv;
    ds = fminf(fmaxf(ds, 0.1f), 10.0f);
    p.out[2 * TNEW * 5 + n * 5 + c] = ds;
  }
}

extern "C" void kernel_launch(void* const* d_in, const int* in_sizes, int n_in,
                              void* d_out, int out_size, void* d_ws, size_t ws_size,
                              hipStream_t stream) {
  char* w = (char*)d_ws;
  P p;
  p.rawNew = (const unsigned int*)d_in[0];
  p.rawOld = (const unsigned int*)d_in[1];
  p.occ    = (const float*)d_in[2];
  p.ncc    = (const float*)d_in[3];
  p.verts  = (const float*)d_in[4];
  p.out    = (float*)d_out;
  p.tkeys    = (unsigned long long*)(w + OFF_TKEYS);
  p.ftab     = (unsigned long long*)(w + OFF_FTAB);
  p.nbr      = (int*)(w + OFF_NBR);
  p.counters = (int*)(w + OFF_CNT);
  p.tvals    = (int*)(w + OFF_TVALS);
  p.pprio    = (int*)(w + OFF_PPRIO);
  p.idxOld   = (int*)(w + OFF_IDXOLD);
  p.cur      = (int*)(w + OFF_CUR);
  p.rem      = (int*)(w + OFF_REM);
  p.degen    = (int*)(w + OFF_DEGEN);
  p.listA    = (int*)(w + OFF_LISTA);
  p.listB    = (int*)(w + OFF_LISTB);
  p.matched  = (int*)(w + OFF_MATCHED);
  p.Tv4      = (float4*)(w + OFF_TV4);
  p.cold4    = (float4*)(w + OFF_COLD4);
  p.cnew4    = (float4*)(w + OFF_CNEW4);
  p.dm       = (unsigned int*)(w + OFF_DM);
  size_t avail = (ws_size > (size_t)OFF_DM) ? ws_size - (size_t)OFF_DM : 0;
  unsigned dmMask = 0;
  for (int bshift = 21; bshift >= 16; --bshift){
    if (avail >= ((size_t)4 << bshift)){ dmMask = (1u << bshift) - 1u; break; }
  }
  p.dmMask = dmMask;

  hipMemsetAsync(w, 0xFF, FF_BYTES, stream);
  hipLaunchKernelGGL(k_setup,    dim3((TOLD + 255) / 256), dim3(256), 0, stream, p);
  hipLaunchKernelGGL(k_prio2,    dim3(NWGR * NSLICE), dim3(256), 0, stream, p);
  hipLaunchKernelGGL(k_face,     dim3((TOLD * 4 + 255) / 256), dim3(256), 0, stream, p);
  hipLaunchKernelGGL(k_new,      dim3((TNEW + 255) / 256), dim3(256), 0, stream, p);
  hipLaunchKernelGGL(k_persist,  dim3(1), dim3(1024), 0, stream, p);
  hipLaunchKernelGGL(k_fallback, dim3(120), dim3(256), 0, stream, p);
  hipLaunchKernelGGL(k_assemble, dim3((TNEW + 255) / 256), dim3(256), 0, stream, p);
}

// Round 7
// 130.642 us; speedup vs baseline: 2.2374x; 1.0928x over previous
//
#include <hip/hip_runtime.h>

#pragma clang fp contract(off)

#define TOLD 60000
#define TNEW 60000
#define NVERT 30000
#define MAXSTEPS 300
#define THSZ 131072                  // tet-key hash slots (exact, CAS)
#define FHSZ 131072                  // exact CAS face table (DM-collision fallback only)
#define EMPTY64 0xFFFFFFFFFFFFFFFFULL
#define NWGR 60                      // prio vertex ranges (500 verts each)
#define VRANGE 500
#define NSLICE 16                    // prio tet slices
#define TSLICE (TOLD / NSLICE)       // 3750

// K1 block-range split
#define NB_SETUP 235                 // ceil(60000/256)
#define NB_PRIO  (NWGR * NSLICE)     // 960
#define NB_NEWG  235                 // ceil(60000/256)
// K2 block-range split
#define NB_FACE  938                 // ceil(240000/256)
#define NB_FOLD  118                 // ceil(30000/256)

// workspace layout: [0xFF-init region][rest, no init needed]
#define OFF_TKEYS    0u              // 131072*8 = 1,048,576
#define OFF_FTAB     1048576u        // 131072*8 = 1,048,576
#define OFF_NBR      2097152u        // 240000*4 =   960,000
#define FF_BYTES     3057152u        // end of 0xFF region
#define OFF_CNT      3057152u        // 256 B (zeroed by k_front block 0)
#define OFF_TVALS    3057408u        // 524,288 (poison-safe: atomicMax vs negative poison)
#define OFF_PPRIO    3581696u        // 16*30000*4 = 1,920,000 (fully written by prio2 part)
#define OFF_PRIO     5501696u        // 120,000 (fully written by fold part)
#define OFF_IDXOLD   5621696u        // 960,000 (16B aligned)
#define OFF_CUR      6581696u        // 240,000
#define OFF_REM      6821696u        // 240,000
#define OFF_DEGEN    7061696u        // 240,000
#define OFF_LISTA    7301696u        // 240,000
#define OFF_LISTB    7541696u        // 240,000
#define OFF_MATCHED  7781696u        // 240,000
#define OFF_TV4      8021696u        // 2,880,000 (3 float4/tet: Tinv row + v0 comp)
#define OFF_COLD4    10901696u       // 960,000 (centroid, oel)
#define OFF_CNEW4    11861696u       // 960,000 (centroid, nel)
#define OFF_DM       12821696u       // direct-mapped face table (uninit/poison-safe)

struct P {
  const unsigned int* rawNew;
  const unsigned int* rawOld;
  const float* occ;
  const float* ncc;
  const float* verts;
  float* out;
  unsigned long long* tkeys;
  unsigned long long* ftab;
  int* counters;   // [0]=n_walk/listB cnt [1]=cntA [2]=cntB(pp) [4]=finalCnt [5]=finalList
  int* tvals;
  int* idxOld;
  int* nbr;
  int* pprio;                        // partial prio (NSLICE, NVERT)
  int* prio;                         // folded prio (NVERT)
  int* cur; int* rem;
  int* degen;
  int* listA; int* listB;
  int* matched;
  float4* Tv4;
  float4* cold4;
  float4* cnew4;
  unsigned int* dm;
  unsigned int dmMask;               // 0 => DM pass disabled (all faces via exact CAS)
};

__device__ __forceinline__ unsigned hash64(unsigned long long k){
  k ^= k >> 33; k *= 0xff51afd7ed558ccdULL;
  k ^= k >> 33; k *= 0xc4ceb9fe1a85ec53ULL;
  k ^= k >> 33;
  return (unsigned)k;
}
__device__ __forceinline__ void cswap(int& a, int& b){ if (a > b){ int t = a; a = b; b = t; } }

// int64 buffers (values in [0,2^31)) have zero high words at odd u32 positions;
// int32 buffers have col1 >= 1 at flat position 1.
__device__ __forceinline__ int detect64(const unsigned int* raw){
  unsigned acc = 0;
  const uint4* r4 = (const uint4*)raw;
  #pragma unroll
  for (int k = 0; k < 32; ++k){ uint4 v = r4[k]; acc |= (v.y | v.w); }
  return acc == 0u;
}

// whole tet record via dwordx4 loads (2 for int64, 1 for int32)
__device__ __forceinline__ int4 load_tet4(const unsigned int* raw, int is64, int t){
  if (is64){
    uint4 a = ((const uint4*)raw)[t * 2 + 0];
    uint4 b = ((const uint4*)raw)[t * 2 + 1];
    return make_int4((int)a.x, (int)a.z, (int)b.x, (int)b.z);
  }
  uint4 a = ((const uint4*)raw)[t];
  return make_int4((int)a.x, (int)a.y, (int)a.z, (int)a.w);
}

// Exact open-addressing face insert (fallback for DM collisions only).
__device__ __forceinline__ void face_insert(unsigned long long* ftab, int* nbr,
                                            unsigned long long fkey, int t, int l){
  unsigned long long mine = (fkey << 18) | (unsigned long long)(t * 4 + l);
  unsigned slot = hash64(fkey ^ 0x9e3779b97f4a7c15ULL) & (FHSZ - 1);
  while (true){
    unsigned long long prev = atomicCAS(&ftab[slot], EMPTY64, mine);
    if (prev == EMPTY64) return;
    if ((prev >> 18) == fkey){
      int oid = (int)(prev & 0x3FFFFULL);
      nbr[t * 4 + l] = oid >> 2;
      nbr[oid] = t;
      return;
    }
    slot = (slot + 1) & (FHSZ - 1);
  }
}

// min edge length; fold order matches the reference EDGES list exactly.
__device__ __forceinline__ float min_edge_r(
    float q0x, float q0y, float q0z, float q1x, float q1y, float q1z,
    float q2x, float q2y, float q2z, float q3x, float q3y, float q3z){
  float m = 3.402823466e+38f;
  float dx, dy, dz, d;
  dx = q0x - q1x; dy = q0y - q1y; dz = q0z - q1z; d = sqrtf((dx*dx + dy*dy) + dz*dz); m = fminf(m, d);
  dx = q0x - q2x; dy = q0y - q2y; dz = q0z - q2z; d = sqrtf((dx*dx + dy*dy) + dz*dz); m = fminf(m, d);
  dx = q0x - q3x; dy = q0y - q3y; dz = q0z - q3z; d = sqrtf((dx*dx + dy*dy) + dz*dz); m = fminf(m, d);
  dx = q1x - q2x; dy = q1y - q2y; dz = q1z - q2z; d = sqrtf((dx*dx + dy*dy) + dz*dz); m = fminf(m, d);
  dx = q1x - q3x; dy = q1y - q3y; dz = q1z - q3z; d = sqrtf((dx*dx + dy*dy) + dz*dz); m = fminf(m, d);
  dx = q2x - q3x; dy = q2y - q3y; dz = q2z - q3z; d = sqrtf((dx*dx + dy*dy) + dz*dz); m = fminf(m, d);
  return m;
}

// K1: three independent phases fused by block range.
//  [0,235)      old-tet setup: idx normalize, tet-key CAS+atomicMax, DM face
//               writes, Tinv/v0/centroid/min-edge geometry
//  [235,1195)   prio partial-max (range,slice) -> pprio, zero fabric atomics
//  [1195,1430)  new-tet geometry: centroid + min-edge -> cnew4
__global__ __launch_bounds__(256) void k_front(P p){
  __shared__ int sprio[VRANGE];
  int bb = blockIdx.x;
  if (bb < NB_SETUP){
    int t = bb * 256 + threadIdx.x;
    if (bb == 0 && threadIdx.x < 64) p.counters[threadIdx.x] = 0;
    if (t >= TOLD) return;
    int is64 = detect64(p.rawOld);
    int4 iv4 = load_tet4(p.rawOld, is64, t);
    int i0 = iv4.x, i1 = iv4.y, i2 = iv4.z, i3 = iv4.w;
    ((int4*)p.idxOld)[t] = iv4;

    // tet key insert; duplicate keys keep MAX tet id (exact: atomicMax always).
    // tvals needs no init: 0xAA poison is a large negative int, always loses.
    {
      int s0 = i0, s1 = i1, s2 = i2, s3 = i3;
      cswap(s0, s1); cswap(s2, s3); cswap(s0, s2); cswap(s1, s3); cswap(s1, s2);
      unsigned long long key =
          (unsigned long long)((((long long)s0 * NVERT + s1) * NVERT + s2) * NVERT + s3);
      unsigned slot = hash64(key) & (THSZ - 1);
      while (true){
        unsigned long long prev = atomicCAS(&p.tkeys[slot], EMPTY64, key);
        if (prev == EMPTY64 || prev == key){ atomicMax(&p.tvals[slot], t); break; }
        slot = (slot + 1) & (THSZ - 1);
      }
    }

    // direct-mapped face id writes (racy last-wins; resolved in k_mid)
    if (p.dmMask){
      const int FO[4][3] = {{1, 2, 3}, {0, 2, 3}, {0, 1, 3}, {0, 1, 2}};
      int iv[4] = {i0, i1, i2, i3};
      #pragma unroll
      for (int l = 0; l < 4; ++l){
        int a = iv[FO[l][0]], b = iv[FO[l][1]], c = iv[FO[l][2]];
        cswap(a, b); cswap(a, c); cswap(b, c);
        unsigned long long fk = (unsigned long long)(((long long)a * NVERT + b) * NVERT + c);
        p.dm[hash64(fk) & p.dmMask] = (unsigned)(t * 4 + l);
      }
    }

    // geometry: Tinv (adjugate/det), v0, centroid, min edge length
    float q0x = p.verts[i0 * 3 + 0], q0y = p.verts[i0 * 3 + 1], q0z = p.verts[i0 * 3 + 2];
    float q1x = p.verts[i1 * 3 + 0], q1y = p.verts[i1 * 3 + 1], q1z = p.verts[i1 * 3 + 2];
    float q2x = p.verts[i2 * 3 + 0], q2y = p.verts[i2 * 3 + 1], q2z = p.verts[i2 * 3 + 2];
    float q3x = p.verts[i3 * 3 + 0], q3y = p.verts[i3 * 3 + 1], q3z = p.verts[i3 * 3 + 2];
    float e1x = q1x - q0x, e1y = q1y - q0y, e1z = q1z - q0z;
    float e2x = q2x - q0x, e2y = q2y - q0y, e2z = q2z - q0z;
    float e3x = q3x - q0x, e3y = q3y - q0y, e3z = q3z - q0z;
    float c23x = e2y * e3z - e2z * e3y;
    float c23y = e2z * e3x - e2x * e3z;
    float c23z = e2x * e3y - e2y * e3x;
    float det = e1x * c23x + e1y * c23y + e1z * c23z;
    int dg = (fabsf(det) < 1e-10f) ? 1 : 0;
    p.degen[t] = dg;
    float4 r0, r1, r2;
    if (dg){
      r0 = make_float4(1.f, 0.f, 0.f, q0x);
      r1 = make_float4(0.f, 1.f, 0.f, q0y);
      r2 = make_float4(0.f, 0.f, 1.f, q0z);
    } else {
      float inv = 1.0f / det;
      float c31x = e3y * e1z - e3z * e1y;
      float c31y = e3z * e1x - e3x * e1z;
      float c31z = e3x * e1y - e3y * e1x;
      float c12x = e1y * e2z - e1z * e2y;
      float c12y = e1z * e2x - e1x * e2z;
      float c12z = e1x * e2y - e1y * e2x;
      r0 = make_float4(c23x * inv, c23y * inv, c23z * inv, q0x);
      r1 = make_float4(c31x * inv, c31y * inv, c31z * inv, q0y);
      r2 = make_float4(c12x * inv, c12y * inv, c12z * inv, q0z);
    }
    p.Tv4[t * 3 + 0] = r0;
    p.Tv4[t * 3 + 1] = r1;
    p.Tv4[t * 3 + 2] = r2;
    float el = min_edge_r(q0x, q0y, q0z, q1x, q1y, q1z, q2x, q2y, q2z, q3x, q3y, q3z);
    p.cold4[t] = make_float4((((q0x + q1x) + q2x) + q3x) * 0.25f,
                             (((q0y + q1y) + q2y) + q3y) * 0.25f,
                             (((q0z + q1z) + q2z) + q3z) * 0.25f, el);
  } else if (bb < NB_SETUP + NB_PRIO){
    int rb = bb - NB_SETUP;
    int range = rb / NSLICE;
    int slice = rb % NSLICE;
    int base = range * VRANGE;
    for (int j = threadIdx.x; j < VRANGE; j += 256) sprio[j] = -1;
    __syncthreads();
    int is64 = detect64(p.rawOld);
    int t0 = slice * TSLICE;
    for (int t = t0 + threadIdx.x; t < t0 + TSLICE; t += 256){
      int4 iv = load_tet4(p.rawOld, is64, t);
      int v;
      v = iv.x - base; if ((unsigned)v < VRANGE) atomicMax(&sprio[v], 0 * TOLD + t);
      v = iv.y - base; if ((unsigned)v < VRANGE) atomicMax(&sprio[v], 1 * TOLD + t);
      v = iv.z - base; if ((unsigned)v < VRANGE) atomicMax(&sprio[v], 2 * TOLD + t);
      v = iv.w - base; if ((unsigned)v < VRANGE) atomicMax(&sprio[v], 3 * TOLD + t);
    }
    __syncthreads();
    for (int j = threadIdx.x; j < VRANGE; j += 256)
      p.pprio[slice * NVERT + base + j] = sprio[j];
  } else {
    int n = (bb - NB_SETUP - NB_PRIO) * 256 + threadIdx.x;
    if (n >= TNEW) return;
    int is64 = detect64(p.rawNew);
    int4 ni = load_tet4(p.rawNew, is64, n);
    float q0x = p.verts[ni.x * 3 + 0], q0y = p.verts[ni.x * 3 + 1], q0z = p.verts[ni.x * 3 + 2];
    float q1x = p.verts[ni.y * 3 + 0], q1y = p.verts[ni.y * 3 + 1], q1z = p.verts[ni.y * 3 + 2];
    float q2x = p.verts[ni.z * 3 + 0], q2y = p.verts[ni.z * 3 + 1], q2z = p.verts[ni.z * 3 + 2];
    float q3x = p.verts[ni.w * 3 + 0], q3y = p.verts[ni.w * 3 + 1], q3z = p.verts[ni.w * 3 + 2];
    float el = min_edge_r(q0x, q0y, q0z, q1x, q1y, q1z, q2x, q2y, q2z, q3x, q3y, q3z);
    p.cnew4[n] = make_float4((((q0x + q1x) + q2x) + q3x) * 0.25f,
                             (((q0y + q1y) + q2y) + q3y) * 0.25f,
                             (((q0z + q1z) + q2z) + q3z) * 0.25f, el);
  }
}

// K2: face resolve [0,938) + pprio 16->1 fold [938,1056).
// Face pair members read the SAME stable DM slot -> symmetric resolution, exact.
__global__ __launch_bounds__(256) void k_mid(P p){
  int bb = blockIdx.x;
  if (bb < NB_FACE){
    int i = bb * 256 + threadIdx.x;
    if (i >= TOLD * 4) return;
    int t = i >> 2, l = i & 3;
    int4 iv4 = ((const int4*)p.idxOld)[t];
    int iv[4] = {iv4.x, iv4.y, iv4.z, iv4.w};
    const int FO[4][3] = {{1, 2, 3}, {0, 2, 3}, {0, 1, 3}, {0, 1, 2}};
    int a = iv[FO[l][0]], b = iv[FO[l][1]], c = iv[FO[l][2]];
    cswap(a, b); cswap(a, c); cswap(b, c);
    unsigned long long fk = (unsigned long long)(((long long)a * NVERT + b) * NVERT + c);
    if (p.dmMask){
      unsigned wid = p.dm[hash64(fk) & p.dmMask];
      if (wid == (unsigned)i) return;                // self-winner; partner links if real
      if (wid < (unsigned)(TOLD * 4)){
        int wt = wid >> 2, wl = (int)(wid & 3u);
        int4 wv4 = ((const int4*)p.idxOld)[wt];
        int wv[4] = {wv4.x, wv4.y, wv4.z, wv4.w};
        int wa = wv[FO[wl][0]], wb = wv[FO[wl][1]], wc = wv[FO[wl][2]];
        cswap(wa, wb); cswap(wa, wc); cswap(wb, wc);
        unsigned long long wfk = (unsigned long long)(((long long)wa * NVERT + wb) * NVERT + wc);
        if (wfk == fk){                              // pair found; plain mutual link
          p.nbr[i] = wt;
          p.nbr[wid] = t;
          return;
        }
      }
    }
    face_insert(p.ftab, p.nbr, fk, t, l);            // exact path for DM collisions
  } else {
    int v = (bb - NB_FACE) * 256 + threadIdx.x;
    if (v >= NVERT) return;
    int pr = -1;
    #pragma unroll
    for (int s = 0; s < NSLICE; ++s) pr = max(pr, p.pprio[s * NVERT + v]);
    p.prio[v] = pr;
  }
}

__device__ __forceinline__ bool walk_step(const P& p, int n){
  int c = p.cur[n];
  float4 r0 = p.Tv4[c * 3 + 0];
  float4 r1 = p.Tv4[c * 3 + 1];
  float4 r2 = p.Tv4[c * 3 + 2];
  float4 cn = p.cnew4[n];
  float rx = cn.x - r0.w, ry = cn.y - r1.w, rz = cn.z - r2.w;
  float b0 = r0.x * rx + r0.y * ry + r0.z * rz;
  float b1 = r1.x * rx + r1.y * ry + r1.z * rz;
  float b2 = r2.x * rx + r2.y * ry + r2.z * rz;
  float a0 = 1.0f - (b0 + b1 + b2);
  float ab[4] = {a0, b0, b1, b2};
  int amin = 0; float mn = ab[0];
  for (int j = 1; j < 4; ++j){ if (ab[j] < mn){ mn = ab[j]; amin = j; } }
  if (mn >= -0.0001f){ p.rem[n] = c; return false; }
  int nb = p.degen[c] ? -1 : p.nbr[c * 4 + amin];
  if (nb < 0){ p.rem[n] = c; return false; }
  p.cur[n] = nb;
  return true;
}

// K3: hash match + seed + SPECULATIVE walk body #1. If n_walk < 100 the
// reference ran no steps, but then fallback overrides rem for every unmatched
// walker, so the speculative writes are dead. listB = all unmatched (nw<100
// path), listA = step-1 survivors (nw>=100 path).
__global__ __launch_bounds__(256) void k_new2(P p){
  int n = blockIdx.x * blockDim.x + threadIdx.x;
  if (n >= TNEW) return;
  int is64 = detect64(p.rawNew);
  int4 ni = load_tet4(p.rawNew, is64, n);
  int s0 = ni.x, s1 = ni.y, s2 = ni.z, s3 = ni.w;
  cswap(s0, s1); cswap(s2, s3); cswap(s0, s2); cswap(s1, s3); cswap(s1, s2);
  unsigned long long key =
      (unsigned long long)((((long long)s0 * NVERT + s1) * NVERT + s2) * NVERT + s3);
  int m = -1;
  {
    unsigned slot = hash64(key) & (THSZ - 1);
    while (true){
      unsigned long long k = p.tkeys[slot];
      if (k == EMPTY64) break;
      if (k == key){ m = p.tvals[slot]; break; }
      slot = (slot + 1) & (THSZ - 1);
    }
  }
  p.matched[n] = m;
  if (m >= 0) return;
  int pr = p.prio[ni.x];
  int seed = (pr >= 0) ? (pr % TOLD) : 0;
  p.cur[n] = seed;
  p.rem[n] = seed;
  p.listB[atomicAdd(&p.counters[0], 1)] = n;         // all-unmatched list (nw<100 path)
  if (walk_step(p, n))
    p.listA[atomicAdd(&p.counters[1], 1)] = n;       // step-1 survivors (nw>=100 path)
}

__global__ void __launch_bounds__(1024) k_persist(P p){
  __shared__ int s_cnt;
  int nw = p.counters[0];
  if (nw < 100){
    // reference while-loop never ran; every unmatched walker goes to fallback
    if (threadIdx.x == 0){ p.counters[4] = nw; p.counters[5] = 1; }
    return;
  }
  int thr = max(100, nw / 1000);
  if (threadIdx.x == 0) s_cnt = atomicAdd(&p.counters[1], 0);
  __syncthreads();
  int count = s_cnt;
  int use_a = 1;
  int step = 1;                        // k_new2 performed body #1
  while (step < MAXSTEPS && count >= thr){
    int* curL = use_a ? p.listA : p.listB;
    int* nxtL = use_a ? p.listB : p.listA;
    int* nxtC = use_a ? &p.counters[2] : &p.counters[1];
    int* curC = use_a ? &p.counters[1] : &p.counters[2];
    for (int i = threadIdx.x; i < count; i += blockDim.x){
      int n = curL[i];
      if (walk_step(p, n)){
        int pos = atomicAdd(nxtC, 1);
        nxtL[pos] = n;
      }
    }
    __syncthreads();
    if (threadIdx.x == 0){
      s_cnt = atomicAdd(nxtC, 0);
      atomicExch(curC, 0);
    }
    __syncthreads();
    count = s_cnt;
    use_a ^= 1;
    ++step;
  }
  if (threadIdx.x == 0){
    p.counters[4] = count;
    p.counters[5] = use_a ? 0 : 1;     // 0=listA holds final actives, 1=listB
  }
}

// Nearest-old-centroid fallback for final actives only. Reference tie-break
// == first index achieving the global float min.
__global__ __launch_bounds__(256) void k_fallback(P p){
  __shared__ float sd[256];
  __shared__ int si[256];
  int fc = p.counters[4];
  const int* lst = p.counters[5] ? p.listB : p.listA;
  for (int e = blockIdx.x; e < fc; e += gridDim.x){
    int n = lst[e];
    float4 cn = p.cnew4[n];
    float cx = cn.x, cy = cn.y, cz = cn.z;
    float p2 = (cx * cx + cy * cy) + cz * cz;
    float bd = 3.402823466e+38f; int bi = 0;
    for (int j = threadIdx.x; j < TOLD; j += 256){
      float4 oc = p.cold4[j];
      float dot = (cx * oc.x + cy * oc.y) + cz * oc.z;
      float c2 = (oc.x * oc.x + oc.y * oc.y) + oc.z * oc.z;
      float d = (p2 - 2.0f * dot) + c2;
      if (d < bd || (d == bd && j < bi)){ bd = d; bi = j; }
    }
    sd[threadIdx.x] = bd; si[threadIdx.x] = bi;
    __syncthreads();
    for (int s = 128; s > 0; s >>= 1){
      if ((int)threadIdx.x < s){
        float od = sd[threadIdx.x + s]; int oi = si[threadIdx.x + s];
        if (od < sd[threadIdx.x] || (od == sd[threadIdx.x] && oi < si[threadIdx.x])){
          sd[threadIdx.x] = od; si[threadIdx.x] = oi;
        }
      }
      __syncthreads();
    }
    if (threadIdx.x == 0){
      int r = si[0];
      if (r < 0) r = 0; if (r > TOLD - 1) r = TOLD - 1;
      p.rem[n] = r;
    }
    __syncthreads();
  }
}

__global__ __launch_bounds__(256) void k_assemble(P p){
  int n = blockIdx.x * blockDim.x + threadIdx.x;
  if (n >= TNEW) return;
  int m = p.matched[n];
  int remap = (m >= 0) ? m : p.rem[n];
  int cds[5];
  cds[0] = remap;
  int dg = p.degen[remap];
  int4 nb4 = ((const int4*)p.nbr)[remap];
  int nbl[4] = {nb4.x, nb4.y, nb4.z, nb4.w};
  for (int l = 0; l < 4; ++l){
    int fb = dg ? -1 : nbl[l];
    cds[1 + l] = (fb >= 0) ? fb : remap;
  }
  if (m >= 0){ for (int c = 0; c < 5; ++c) cds[c] = m; }
  int is64 = detect64(p.rawNew);
  int4 ni = load_tet4(p.rawNew, is64, n);
  float nc0 = p.ncc[n * 3 + 0], nc1 = p.ncc[n * 3 + 1], nc2 = p.ncc[n * 3 + 2];
  float raws[5]; float rsum = 0.0f;
  float oels[5];
  for (int c = 0; c < 5; ++c){
    int ct = cds[c];
    int4 cv = ((const int4*)p.idxOld)[ct];
    int ov = 0;
    ov += (cv.x == ni.x || cv.x == ni.y || cv.x == ni.z || cv.x == ni.w) ? 1 : 0;
    ov += (cv.y == ni.x || cv.y == ni.y || cv.y == ni.z || cv.y == ni.w) ? 1 : 0;
    ov += (cv.z == ni.x || cv.z == ni.y || cv.z == ni.z || cv.z == ni.w) ? 1 : 0;
    ov += (cv.w == ni.x || cv.w == ni.y || cv.w == ni.z || cv.w == ni.w) ? 1 : 0;
    float d0 = p.occ[ct * 3 + 0] - nc0;
    float d1 = p.occ[ct * 3 + 1] - nc1;
    float d2 = p.occ[ct * 3 + 2] - nc2;
    float ccd2 = (d0 * d0 + d1 * d1) + d2 * d2;
    float raw = expf((float)ov * 2.0f) / (ccd2 + 1e-8f);
    raws[c] = raw; rsum += raw;
    oels[c] = p.cold4[ct].w;
  }
  float nelv = fmaxf(p.cnew4[n].w, 1e-8f);
  for (int c = 0; c < 5; ++c){
    p.out[n * 5 + c] = (float)cds[c];
    p.out[TNEW * 5 + n * 5 + c] = raws[c] / rsum;
    float ds = oels[c] / nelv;
    ds = fminf(fmaxf(ds, 0.1f), 10.0f);
    p.out[2 * TNEW * 5 + n * 5 + c] = ds;
  }
}

extern "C" void kernel_launch(void* const* d_in, const int* in_sizes, int n_in,
                              void* d_out, int out_size, void* d_ws, size_t ws_size,
                              hipStream_t stream) {
  char* w = (char*)d_ws;
  P p;
  p.rawNew = (const unsigned int*)d_in[0];
  p.rawOld = (const unsigned int*)d_in[1];
  p.occ    = (const float*)d_in[2];
  p.ncc    = (const float*)d_in[3];
  p.verts  = (const float*)d_in[4];
  p.out    = (float*)d_out;
  p.tkeys    = (unsigned long long*)(w + OFF_TKEYS);
  p.ftab     = (unsigned long long*)(w + OFF_FTAB);
  p.nbr      = (int*)(w + OFF_NBR);
  p.counters = (int*)(w + OFF_CNT);
  p.tvals    = (int*)(w + OFF_TVALS);
  p.pprio    = (int*)(w + OFF_PPRIO);
  p.prio     = (int*)(w + OFF_PRIO);
  p.idxOld   = (int*)(w + OFF_IDXOLD);
  p.cur      = (int*)(w + OFF_CUR);
  p.rem      = (int*)(w + OFF_REM);
  p.degen    = (int*)(w + OFF_DEGEN);
  p.listA    = (int*)(w + OFF_LISTA);
  p.listB    = (int*)(w + OFF_LISTB);
  p.matched  = (int*)(w + OFF_MATCHED);
  p.Tv4      = (float4*)(w + OFF_TV4);
  p.cold4    = (float4*)(w + OFF_COLD4);
  p.cnew4    = (float4*)(w + OFF_CNEW4);
  p.dm       = (unsigned int*)(w + OFF_DM);
  size_t avail = (ws_size > (size_t)OFF_DM) ? ws_size - (size_t)OFF_DM : 0;
  unsigned dmMask = 0;
  for (int bshift = 21; bshift >= 16; --bshift){
    if (avail >= ((size_t)4 << bshift)){ dmMask = (1u << bshift) - 1u; break; }
  }
  p.dmMask = dmMask;

  hipMemsetAsync(w, 0xFF, FF_BYTES, stream);
  hipLaunchKernelGGL(k_front,    dim3(NB_SETUP + NB_PRIO + NB_NEWG), dim3(256), 0, stream, p);
  hipLaunchKernelGGL(k_mid,      dim3(NB_FACE + NB_FOLD), dim3(256), 0, stream, p);
  hipLaunchKernelGGL(k_new2,     dim3((TNEW + 255) / 256), dim3(256), 0, stream, p);
  hipLaunchKernelGGL(k_persist,  dim3(1), dim3(1024), 0, stream, p);
  hipLaunchKernelGGL(k_fallback, dim3(120), dim3(256), 0, stream, p);
  hipLaunchKernelGGL(k_assemble, dim3((TNEW + 255) / 256), dim3(256), 0, stream, p);
}

// Round 8
// 123.945 us; speedup vs baseline: 2.3583x; 1.0540x over previous
//
#include <hip/hip_runtime.h>

#pragma clang fp contract(off)

#define TOLD 60000
#define TNEW 60000
#define NVERT 30000
#define MAXSTEPS 300
#define THSZ 131072                  // tet-key hash slots (exact, CAS)
#define FHSZ 131072                  // exact CAS face table (DM-collision fallback only)
#define EMPTY64 0xFFFFFFFFFFFFFFFFULL
#define NWGR 60                      // prio vertex ranges (500 verts each)
#define VRANGE 500
#define NSLICE 16                    // prio tet slices
#define TSLICE (TOLD / NSLICE)       // 3750

// K1 block-range split
#define NB_SETUP 235                 // ceil(60000/256)
#define NB_PRIO  (NWGR * NSLICE)     // 960
#define NB_NEWG  235
// K2 block-range split
#define NB_FACE  938                 // ceil(240000/256)
#define NB_FOLD  118                 // ceil(30000/256)
#define NB_MATCH 235                 // tet-match probe for new tets
// K_tail block-range split
#define NB_FB    120                 // fallback blocks (inline assemble)
#define NB_ASM   235

// workspace layout: [0xFF-init region][rest, no init needed]
#define OFF_TKEYS    0u              // 131072*8 = 1,048,576
#define OFF_FTAB     1048576u        // 131072*8 = 1,048,576
#define OFF_NBR      2097152u        // 240000*4 =   960,000
#define FF_BYTES     3057152u        // end of 0xFF region
#define OFF_CNT      3057152u        // 256 B (zeroed by k_front block 0)
#define OFF_TVALS    3057408u        // 524,288 (poison-safe)
#define OFF_PPRIO    3581696u        // 1,920,000 (fully written by prio2 part)
#define OFF_PRIO     5501696u        // 120,000 (fully written by fold part)
#define OFF_IDXOLD   5621696u        // 960,000 (16B aligned)
#define OFF_CUR      6581696u        // 240,000
#define OFF_REM      6821696u        // 240,000
#define OFF_DEGEN    7061696u        // 240,000
#define OFF_LISTA    7301696u        // 240,000
#define OFF_LISTB    7541696u        // 240,000
#define OFF_MATCHED  7781696u        // 240,000
#define OFF_TV4      8021696u        // 2,880,000 (3 float4/tet: Tinv row + v0 comp)
#define OFF_COLD4    10901696u       // 960,000 (centroid, oel)
#define OFF_CNEW4    11861696u       // 960,000 (centroid, nel)
#define OFF_DM       12821696u       // direct-mapped face table (uninit/poison-safe)

struct P {
  const unsigned int* rawNew;
  const unsigned int* rawOld;
  const float* occ;
  const float* ncc;
  const float* verts;
  float* out;
  unsigned long long* tkeys;
  unsigned long long* ftab;
  int* counters;   // [0]=n_walk [1]=cntA [2]=cntB [4]=finalCnt [5]=finalList
  int* tvals;
  int* idxOld;
  int* nbr;
  int* pprio;
  int* prio;
  int* cur; int* rem;
  int* degen;
  int* listA; int* listB;
  int* matched;
  float4* Tv4;
  float4* cold4;
  float4* cnew4;
  unsigned int* dm;
  unsigned int dmMask;
};

__device__ __forceinline__ unsigned hash64(unsigned long long k){
  k ^= k >> 33; k *= 0xff51afd7ed558ccdULL;
  k ^= k >> 33; k *= 0xc4ceb9fe1a85ec53ULL;
  k ^= k >> 33;
  return (unsigned)k;
}
__device__ __forceinline__ void cswap(int& a, int& b){ if (a > b){ int t = a; a = b; b = t; } }

__device__ __forceinline__ int detect64(const unsigned int* raw){
  unsigned acc = 0;
  const uint4* r4 = (const uint4*)raw;
  #pragma unroll
  for (int k = 0; k < 32; ++k){ uint4 v = r4[k]; acc |= (v.y | v.w); }
  return acc == 0u;
}

__device__ __forceinline__ int4 load_tet4(const unsigned int* raw, int is64, int t){
  if (is64){
    uint4 a = ((const uint4*)raw)[t * 2 + 0];
    uint4 b = ((const uint4*)raw)[t * 2 + 1];
    return make_int4((int)a.x, (int)a.z, (int)b.x, (int)b.z);
  }
  uint4 a = ((const uint4*)raw)[t];
  return make_int4((int)a.x, (int)a.y, (int)a.z, (int)a.w);
}

__device__ __forceinline__ void face_insert(unsigned long long* ftab, int* nbr,
                                            unsigned long long fkey, int t, int l){
  unsigned long long mine = (fkey << 18) | (unsigned long long)(t * 4 + l);
  unsigned slot = hash64(fkey ^ 0x9e3779b97f4a7c15ULL) & (FHSZ - 1);
  while (true){
    unsigned long long prev = atomicCAS(&ftab[slot], EMPTY64, mine);
    if (prev == EMPTY64) return;
    if ((prev >> 18) == fkey){
      int oid = (int)(prev & 0x3FFFFULL);
      nbr[t * 4 + l] = oid >> 2;
      nbr[oid] = t;
      return;
    }
    slot = (slot + 1) & (FHSZ - 1);
  }
}

__device__ __forceinline__ float min_edge_r(
    float q0x, float q0y, float q0z, float q1x, float q1y, float q1z,
    float q2x, float q2y, float q2z, float q3x, float q3y, float q3z){
  float m = 3.402823466e+38f;
  float dx, dy, dz, d;
  dx = q0x - q1x; dy = q0y - q1y; dz = q0z - q1z; d = sqrtf((dx*dx + dy*dy) + dz*dz); m = fminf(m, d);
  dx = q0x - q2x; dy = q0y - q2y; dz = q0z - q2z; d = sqrtf((dx*dx + dy*dy) + dz*dz); m = fminf(m, d);
  dx = q0x - q3x; dy = q0y - q3y; dz = q0z - q3z; d = sqrtf((dx*dx + dy*dy) + dz*dz); m = fminf(m, d);
  dx = q1x - q2x; dy = q1y - q2y; dz = q1z - q2z; d = sqrtf((dx*dx + dy*dy) + dz*dz); m = fminf(m, d);
  dx = q1x - q3x; dy = q1y - q3y; dz = q1z - q3z; d = sqrtf((dx*dx + dy*dy) + dz*dz); m = fminf(m, d);
  dx = q2x - q3x; dy = q2y - q3y; dz = q2z - q3z; d = sqrtf((dx*dx + dy*dy) + dz*dz); m = fminf(m, d);
  return m;
}

// K1: setup [0,235) | prio partial-max [235,1195) | new-geometry [1195,1430)
__global__ __launch_bounds__(256) void k_front(P p){
  __shared__ int sprio[VRANGE];
  int bb = blockIdx.x;
  if (bb < NB_SETUP){
    int t = bb * 256 + threadIdx.x;
    if (bb == 0 && threadIdx.x < 64) p.counters[threadIdx.x] = 0;
    if (t >= TOLD) return;
    int is64 = detect64(p.rawOld);
    int4 iv4 = load_tet4(p.rawOld, is64, t);
    int i0 = iv4.x, i1 = iv4.y, i2 = iv4.z, i3 = iv4.w;
    ((int4*)p.idxOld)[t] = iv4;

    // tet key insert; CAS winner plain-stores value, dup-key path (P~5e-8)
    // uses atomicMax. tvals poison (0xAA.. = negative) always loses the max.
    {
      int s0 = i0, s1 = i1, s2 = i2, s3 = i3;
      cswap(s0, s1); cswap(s2, s3); cswap(s0, s2); cswap(s1, s3); cswap(s1, s2);
      unsigned long long key =
          (unsigned long long)((((long long)s0 * NVERT + s1) * NVERT + s2) * NVERT + s3);
      unsigned slot = hash64(key) & (THSZ - 1);
      while (true){
        unsigned long long prev = atomicCAS(&p.tkeys[slot], EMPTY64, key);
        if (prev == EMPTY64){ p.tvals[slot] = t; break; }
        if (prev == key){ atomicMax(&p.tvals[slot], t); break; }
        slot = (slot + 1) & (THSZ - 1);
      }
    }

    // direct-mapped face id writes (racy last-wins; resolved in k_mid)
    if (p.dmMask){
      const int FO[4][3] = {{1, 2, 3}, {0, 2, 3}, {0, 1, 3}, {0, 1, 2}};
      int iv[4] = {i0, i1, i2, i3};
      #pragma unroll
      for (int l = 0; l < 4; ++l){
        int a = iv[FO[l][0]], b = iv[FO[l][1]], c = iv[FO[l][2]];
        cswap(a, b); cswap(a, c); cswap(b, c);
        unsigned long long fk = (unsigned long long)(((long long)a * NVERT + b) * NVERT + c);
        p.dm[hash64(fk) & p.dmMask] = (unsigned)(t * 4 + l);
      }
    }

    float q0x = p.verts[i0 * 3 + 0], q0y = p.verts[i0 * 3 + 1], q0z = p.verts[i0 * 3 + 2];
    float q1x = p.verts[i1 * 3 + 0], q1y = p.verts[i1 * 3 + 1], q1z = p.verts[i1 * 3 + 2];
    float q2x = p.verts[i2 * 3 + 0], q2y = p.verts[i2 * 3 + 1], q2z = p.verts[i2 * 3 + 2];
    float q3x = p.verts[i3 * 3 + 0], q3y = p.verts[i3 * 3 + 1], q3z = p.verts[i3 * 3 + 2];
    float e1x = q1x - q0x, e1y = q1y - q0y, e1z = q1z - q0z;
    float e2x = q2x - q0x, e2y = q2y - q0y, e2z = q2z - q0z;
    float e3x = q3x - q0x, e3y = q3y - q0y, e3z = q3z - q0z;
    float c23x = e2y * e3z - e2z * e3y;
    float c23y = e2z * e3x - e2x * e3z;
    float c23z = e2x * e3y - e2y * e3x;
    float det = e1x * c23x + e1y * c23y + e1z * c23z;
    int dg = (fabsf(det) < 1e-10f) ? 1 : 0;
    p.degen[t] = dg;
    float4 r0, r1, r2;
    if (dg){
      r0 = make_float4(1.f, 0.f, 0.f, q0x);
      r1 = make_float4(0.f, 1.f, 0.f, q0y);
      r2 = make_float4(0.f, 0.f, 1.f, q0z);
    } else {
      float inv = 1.0f / det;
      float c31x = e3y * e1z - e3z * e1y;
      float c31y = e3z * e1x - e3x * e1z;
      float c31z = e3x * e1y - e3y * e1x;
      float c12x = e1y * e2z - e1z * e2y;
      float c12y = e1z * e2x - e1x * e2z;
      float c12z = e1x * e2y - e1y * e2x;
      r0 = make_float4(c23x * inv, c23y * inv, c23z * inv, q0x);
      r1 = make_float4(c31x * inv, c31y * inv, c31z * inv, q0y);
      r2 = make_float4(c12x * inv, c12y * inv, c12z * inv, q0z);
    }
    p.Tv4[t * 3 + 0] = r0;
    p.Tv4[t * 3 + 1] = r1;
    p.Tv4[t * 3 + 2] = r2;
    float el = min_edge_r(q0x, q0y, q0z, q1x, q1y, q1z, q2x, q2y, q2z, q3x, q3y, q3z);
    p.cold4[t] = make_float4((((q0x + q1x) + q2x) + q3x) * 0.25f,
                             (((q0y + q1y) + q2y) + q3y) * 0.25f,
                             (((q0z + q1z) + q2z) + q3z) * 0.25f, el);
  } else if (bb < NB_SETUP + NB_PRIO){
    int rb = bb - NB_SETUP;
    int range = rb / NSLICE;
    int slice = rb % NSLICE;
    int base = range * VRANGE;
    for (int j = threadIdx.x; j < VRANGE; j += 256) sprio[j] = -1;
    __syncthreads();
    int is64 = detect64(p.rawOld);
    int t0 = slice * TSLICE;
    for (int t = t0 + threadIdx.x; t < t0 + TSLICE; t += 256){
      int4 iv = load_tet4(p.rawOld, is64, t);
      int v;
      v = iv.x - base; if ((unsigned)v < VRANGE) atomicMax(&sprio[v], 0 * TOLD + t);
      v = iv.y - base; if ((unsigned)v < VRANGE) atomicMax(&sprio[v], 1 * TOLD + t);
      v = iv.z - base; if ((unsigned)v < VRANGE) atomicMax(&sprio[v], 2 * TOLD + t);
      v = iv.w - base; if ((unsigned)v < VRANGE) atomicMax(&sprio[v], 3 * TOLD + t);
    }
    __syncthreads();
    for (int j = threadIdx.x; j < VRANGE; j += 256)
      p.pprio[slice * NVERT + base + j] = sprio[j];
  } else {
    int n = (bb - NB_SETUP - NB_PRIO) * 256 + threadIdx.x;
    if (n >= TNEW) return;
    int is64 = detect64(p.rawNew);
    int4 ni = load_tet4(p.rawNew, is64, n);
    float q0x = p.verts[ni.x * 3 + 0], q0y = p.verts[ni.x * 3 + 1], q0z = p.verts[ni.x * 3 + 2];
    float q1x = p.verts[ni.y * 3 + 0], q1y = p.verts[ni.y * 3 + 1], q1z = p.verts[ni.y * 3 + 2];
    float q2x = p.verts[ni.z * 3 + 0], q2y = p.verts[ni.z * 3 + 1], q2z = p.verts[ni.z * 3 + 2];
    float q3x = p.verts[ni.w * 3 + 0], q3y = p.verts[ni.w * 3 + 1], q3z = p.verts[ni.w * 3 + 2];
    float el = min_edge_r(q0x, q0y, q0z, q1x, q1y, q1z, q2x, q2y, q2z, q3x, q3y, q3z);
    p.cnew4[n] = make_float4((((q0x + q1x) + q2x) + q3x) * 0.25f,
                             (((q0y + q1y) + q2y) + q3y) * 0.25f,
                             (((q0z + q1z) + q2z) + q3z) * 0.25f, el);
  }
}

// K2: face resolve [0,938) + pprio fold [938,1056) + new-tet match probe [1056,1291)
__global__ __launch_bounds__(256) void k_mid(P p){
  int bb = blockIdx.x;
  if (bb < NB_FACE){
    int i = bb * 256 + threadIdx.x;
    if (i >= TOLD * 4) return;
    int t = i >> 2, l = i & 3;
    int4 iv4 = ((const int4*)p.idxOld)[t];
    int iv[4] = {iv4.x, iv4.y, iv4.z, iv4.w};
    const int FO[4][3] = {{1, 2, 3}, {0, 2, 3}, {0, 1, 3}, {0, 1, 2}};
    int a = iv[FO[l][0]], b = iv[FO[l][1]], c = iv[FO[l][2]];
    cswap(a, b); cswap(a, c); cswap(b, c);
    unsigned long long fk = (unsigned long long)(((long long)a * NVERT + b) * NVERT + c);
    if (p.dmMask){
      unsigned wid = p.dm[hash64(fk) & p.dmMask];
      if (wid == (unsigned)i) return;                // self-winner
      if (wid < (unsigned)(TOLD * 4)){
        int wt = wid >> 2, wl = (int)(wid & 3u);
        int4 wv4 = ((const int4*)p.idxOld)[wt];
        int wv[4] = {wv4.x, wv4.y, wv4.z, wv4.w};
        int wa = wv[FO[wl][0]], wb = wv[FO[wl][1]], wc = wv[FO[wl][2]];
        cswap(wa, wb); cswap(wa, wc); cswap(wb, wc);
        unsigned long long wfk = (unsigned long long)(((long long)wa * NVERT + wb) * NVERT + wc);
        if (wfk == fk){                              // pair; plain mutual link
          p.nbr[i] = wt;
          p.nbr[wid] = t;
          return;
        }
      }
    }
    face_insert(p.ftab, p.nbr, fk, t, l);
  } else if (bb < NB_FACE + NB_FOLD){
    int v = (bb - NB_FACE) * 256 + threadIdx.x;
    if (v >= NVERT) return;
    int pr = -1;
    #pragma unroll
    for (int s = 0; s < NSLICE; ++s) pr = max(pr, p.pprio[s * NVERT + v]);
    p.prio[v] = pr;
  } else {
    int n = (bb - NB_FACE - NB_FOLD) * 256 + threadIdx.x;
    if (n >= TNEW) return;
    int is64 = detect64(p.rawNew);
    int4 ni = load_tet4(p.rawNew, is64, n);
    int s0 = ni.x, s1 = ni.y, s2 = ni.z, s3 = ni.w;
    cswap(s0, s1); cswap(s2, s3); cswap(s0, s2); cswap(s1, s3); cswap(s1, s2);
    unsigned long long key =
        (unsigned long long)((((long long)s0 * NVERT + s1) * NVERT + s2) * NVERT + s3);
    int m = -1;
    unsigned slot = hash64(key) & (THSZ - 1);
    while (true){
      unsigned long long k = p.tkeys[slot];
      if (k == EMPTY64) break;
      if (k == key){ m = p.tvals[slot]; break; }
      slot = (slot + 1) & (THSZ - 1);
    }
    p.matched[n] = m;
  }
}

__device__ __forceinline__ bool walk_step(const P& p, int n){
  int c = p.cur[n];
  float4 r0 = p.Tv4[c * 3 + 0];
  float4 r1 = p.Tv4[c * 3 + 1];
  float4 r2 = p.Tv4[c * 3 + 2];
  float4 cn = p.cnew4[n];
  float rx = cn.x - r0.w, ry = cn.y - r1.w, rz = cn.z - r2.w;
  float b0 = r0.x * rx + r0.y * ry + r0.z * rz;
  float b1 = r1.x * rx + r1.y * ry + r1.z * rz;
  float b2 = r2.x * rx + r2.y * ry + r2.z * rz;
  float a0 = 1.0f - (b0 + b1 + b2);
  float ab[4] = {a0, b0, b1, b2};
  int amin = 0; float mn = ab[0];
  for (int j = 1; j < 4; ++j){ if (ab[j] < mn){ mn = ab[j]; amin = j; } }
  if (mn >= -0.0001f){ p.rem[n] = c; return false; }
  int nb = p.degen[c] ? -1 : p.nbr[c * 4 + amin];
  if (nb < 0){ p.rem[n] = c; return false; }
  p.cur[n] = nb;
  return true;
}

// K3: seed + SPECULATIVE walk body #1 for unmatched walkers.
__global__ __launch_bounds__(256) void k_new3(P p){
  int n = blockIdx.x * blockDim.x + threadIdx.x;
  if (n >= TNEW) return;
  if (p.matched[n] >= 0) return;
  int is64 = detect64(p.rawNew);
  int i0 = is64 ? (int)((const long long*)p.rawNew)[n * 4] : ((const int*)p.rawNew)[n * 4];
  int pr = p.prio[i0];
  int seed = (pr >= 0) ? (pr % TOLD) : 0;
  p.cur[n] = seed;
  p.rem[n] = seed;
  p.listB[atomicAdd(&p.counters[0], 1)] = n;         // all-unmatched (nw<100 path)
  if (walk_step(p, n))
    p.listA[atomicAdd(&p.counters[1], 1)] = n;       // step-1 survivors
}

// K4: remaining walk iterations; flags final actives with rem = -1 sentinel.
__global__ void __launch_bounds__(1024) k_persist(P p){
  __shared__ int s_cnt;
  int nw = p.counters[0];
  if (nw < 100){
    // reference loop never ran -> every unmatched walker is fallback-bound
    for (int i = threadIdx.x; i < nw; i += blockDim.x) p.rem[p.listB[i]] = -1;
    if (threadIdx.x == 0){ p.counters[4] = nw; p.counters[5] = 1; }
    return;
  }
  int thr = max(100, nw / 1000);
  if (threadIdx.x == 0) s_cnt = atomicAdd(&p.counters[1], 0);
  __syncthreads();
  int count = s_cnt;
  int use_a = 1;
  int step = 1;                        // k_new3 performed body #1
  while (step < MAXSTEPS && count >= thr){
    int* curL = use_a ? p.listA : p.listB;
    int* nxtL = use_a ? p.listB : p.listA;
    int* nxtC = use_a ? &p.counters[2] : &p.counters[1];
    int* curC = use_a ? &p.counters[1] : &p.counters[2];
    for (int i = threadIdx.x; i < count; i += blockDim.x){
      int n = curL[i];
      if (walk_step(p, n)){
        int pos = atomicAdd(nxtC, 1);
        nxtL[pos] = n;
      }
    }
    __syncthreads();
    if (threadIdx.x == 0){
      s_cnt = atomicAdd(nxtC, 0);
      atomicExch(curC, 0);
    }
    __syncthreads();
    count = s_cnt;
    use_a ^= 1;
    ++step;
  }
  const int* fl = use_a ? p.listA : p.listB;
  for (int i = threadIdx.x; i < count; i += blockDim.x) p.rem[fl[i]] = -1;
  if (threadIdx.x == 0){
    p.counters[4] = count;
    p.counters[5] = use_a ? 0 : 1;
  }
}

// Per-walker output assembly. Fast path when all 5 candidates coincide
// (matched, degenerate, or no real neighbors): 1 gather set instead of 5,
// rsum left-fold replicated exactly on equal inputs.
__device__ __forceinline__ void assemble_walker(const P& p, int n, int m, int remap){
  int cds[5];
  if (m >= 0){
    cds[0] = cds[1] = cds[2] = cds[3] = cds[4] = m;
  } else {
    cds[0] = remap;
    int dg = p.degen[remap];
    int4 nb4 = ((const int4*)p.nbr)[remap];
    int nbl[4] = {nb4.x, nb4.y, nb4.z, nb4.w};
    for (int l = 0; l < 4; ++l){
      int fb = dg ? -1 : nbl[l];
      cds[1 + l] = (fb >= 0) ? fb : remap;
    }
  }
  bool same = (cds[1] == cds[0]) & (cds[2] == cds[0]) &
              (cds[3] == cds[0]) & (cds[4] == cds[0]);
  int is64 = detect64(p.rawNew);
  int4 ni = load_tet4(p.rawNew, is64, n);
  float nc0 = p.ncc[n * 3 + 0], nc1 = p.ncc[n * 3 + 1], nc2 = p.ncc[n * 3 + 2];
  float nelv = fmaxf(p.cnew4[n].w, 1e-8f);
  if (same){
    int ct = cds[0];
    int4 cv = ((const int4*)p.idxOld)[ct];
    int ov = 0;
    ov += (cv.x == ni.x || cv.x == ni.y || cv.x == ni.z || cv.x == ni.w) ? 1 : 0;
    ov += (cv.y == ni.x || cv.y == ni.y || cv.y == ni.z || cv.y == ni.w) ? 1 : 0;
    ov += (cv.z == ni.x || cv.z == ni.y || cv.z == ni.z || cv.z == ni.w) ? 1 : 0;
    ov += (cv.w == ni.x || cv.w == ni.y || cv.w == ni.z || cv.w == ni.w) ? 1 : 0;
    float d0 = p.occ[ct * 3 + 0] - nc0;
    float d1 = p.occ[ct * 3 + 1] - nc1;
    float d2 = p.occ[ct * 3 + 2] - nc2;
    float ccd2 = (d0 * d0 + d1 * d1) + d2 * d2;
    float raw = expf((float)ov * 2.0f) / (ccd2 + 1e-8f);
    float rsum = 0.0f;
    rsum += raw; rsum += raw; rsum += raw; rsum += raw; rsum += raw;
    float wgt = raw / rsum;
    float ds = p.cold4[ct].w / nelv;
    ds = fminf(fmaxf(ds, 0.1f), 10.0f);
    float cf = (float)ct;
    for (int c = 0; c < 5; ++c){
      p.out[n * 5 + c] = cf;
      p.out[TNEW * 5 + n * 5 + c] = wgt;
      p.out[2 * TNEW * 5 + n * 5 + c] = ds;
    }
    return;
  }
  float raws[5]; float rsum = 0.0f;
  float oels[5];
  for (int c = 0; c < 5; ++c){
    int ct = cds[c];
    int4 cv = ((const int4*)p.idxOld)[ct];
    int ov = 0;
    ov += (cv.x == ni.x || cv.x == ni.y || cv.x == ni.z || cv.x == ni.w) ? 1 : 0;
    ov += (cv.y == ni.x || cv.y == ni.y || cv.y == ni.z || cv.y == ni.w) ? 1 : 0;
    ov += (cv.z == ni.x || cv.z == ni.y || cv.z == ni.z || cv.z == ni.w) ? 1 : 0;
    ov += (cv.w == ni.x || cv.w == ni.y || cv.w == ni.z || cv.w == ni.w) ? 1 : 0;
    float d0 = p.occ[ct * 3 + 0] - nc0;
    float d1 = p.occ[ct * 3 + 1] - nc1;
    float d2 = p.occ[ct * 3 + 2] - nc2;
    float ccd2 = (d0 * d0 + d1 * d1) + d2 * d2;
    float raw = expf((float)ov * 2.0f) / (ccd2 + 1e-8f);
    raws[c] = raw; rsum += raw;
    oels[c] = p.cold4[ct].w;
  }
  for (int c = 0; c < 5; ++c){
    p.out[n * 5 + c] = (float)cds[c];
    p.out[TNEW * 5 + n * 5 + c] = raws[c] / rsum;
    float ds = oels[c] / nelv;
    ds = fminf(fmaxf(ds, 0.1f), 10.0f);
    p.out[2 * TNEW * 5 + n * 5 + c] = ds;
  }
}

// K5: fallback [0,120) with inline assemble + assemble-others [120,355).
// Disjoint walker sets (rem == -1 marks fallback-owned) -> race-free.
__global__ __launch_bounds__(256) void k_tail(P p){
  __shared__ float sd[256];
  __shared__ int si[256];
  int bb = blockIdx.x;
  if (bb < NB_FB){
    int fc = p.counters[4];
    const int* lst = p.counters[5] ? p.listB : p.listA;
    for (int e = bb; e < fc; e += NB_FB){
      int n = lst[e];
      float4 cn = p.cnew4[n];
      float cx = cn.x, cy = cn.y, cz = cn.z;
      float p2 = (cx * cx + cy * cy) + cz * cz;
      float bd = 3.402823466e+38f; int bi = 0;
      for (int j = threadIdx.x; j < TOLD; j += 256){
        float4 oc = p.cold4[j];
        float dot = (cx * oc.x + cy * oc.y) + cz * oc.z;
        float c2 = (oc.x * oc.x + oc.y * oc.y) + oc.z * oc.z;
        float d = (p2 - 2.0f * dot) + c2;
        if (d < bd || (d == bd && j < bi)){ bd = d; bi = j; }
      }
      sd[threadIdx.x] = bd; si[threadIdx.x] = bi;
      __syncthreads();
      for (int s = 128; s > 0; s >>= 1){
        if ((int)threadIdx.x < s){
          float od = sd[threadIdx.x + s]; int oi = si[threadIdx.x + s];
          if (od < sd[threadIdx.x] || (od == sd[threadIdx.x] && oi < si[threadIdx.x])){
            sd[threadIdx.x] = od; si[threadIdx.x] = oi;
          }
        }
        __syncthreads();
      }
      if (threadIdx.x == 0){
        int r = si[0];
        if (r < 0) r = 0; if (r > TOLD - 1) r = TOLD - 1;
        assemble_walker(p, n, -1, r);
      }
      __syncthreads();
    }
  } else {
    int n = (bb - NB_FB) * 256 + threadIdx.x;
    if (n >= TNEW) return;
    int m = p.matched[n];
    int remap = 0;
    if (m < 0){
      remap = p.rem[n];
      if (remap < 0) return;                         // final-active: fallback blocks own it
    }
    assemble_walker(p, n, m, remap);
  }
}

extern "C" void kernel_launch(void* const* d_in, const int* in_sizes, int n_in,
                              void* d_out, int out_size, void* d_ws, size_t ws_size,
                              hipStream_t stream) {
  char* w = (char*)d_ws;
  P p;
  p.rawNew = (const unsigned int*)d_in[0];
  p.rawOld = (const unsigned int*)d_in[1];
  p.occ    = (const float*)d_in[2];
  p.ncc    = (const float*)d_in[3];
  p.verts  = (const float*)d_in[4];
  p.out    = (float*)d_out;
  p.tkeys    = (unsigned long long*)(w + OFF_TKEYS);
  p.ftab     = (unsigned long long*)(w + OFF_FTAB);
  p.nbr      = (int*)(w + OFF_NBR);
  p.counters = (int*)(w + OFF_CNT);
  p.tvals    = (int*)(w + OFF_TVALS);
  p.pprio    = (int*)(w + OFF_PPRIO);
  p.prio     = (int*)(w + OFF_PRIO);
  p.idxOld   = (int*)(w + OFF_IDXOLD);
  p.cur      = (int*)(w + OFF_CUR);
  p.rem      = (int*)(w + OFF_REM);
  p.degen    = (int*)(w + OFF_DEGEN);
  p.listA    = (int*)(w + OFF_LISTA);
  p.listB    = (int*)(w + OFF_LISTB);
  p.matched  = (int*)(w + OFF_MATCHED);
  p.Tv4      = (float4*)(w + OFF_TV4);
  p.cold4    = (float4*)(w + OFF_COLD4);
  p.cnew4    = (float4*)(w + OFF_CNEW4);
  p.dm       = (unsigned int*)(w + OFF_DM);
  size_t avail = (ws_size > (size_t)OFF_DM) ? ws_size - (size_t)OFF_DM : 0;
  unsigned dmMask = 0;
  for (int bshift = 21; bshift >= 16; --bshift){
    if (avail >= ((size_t)4 << bshift)){ dmMask = (1u << bshift) - 1u; break; }
  }
  p.dmMask = dmMask;

  hipMemsetAsync(w, 0xFF, FF_BYTES, stream);
  hipLaunchKernelGGL(k_front,   dim3(NB_SETUP + NB_PRIO + NB_NEWG), dim3(256), 0, stream, p);
  hipLaunchKernelGGL(k_mid,     dim3(NB_FACE + NB_FOLD + NB_MATCH), dim3(256), 0, stream, p);
  hipLaunchKernelGGL(k_new3,    dim3((TNEW + 255) / 256), dim3(256), 0, stream, p);
  hipLaunchKernelGGL(k_persist, dim3(1), dim3(1024), 0, stream, p);
  hipLaunchKernelGGL(k_tail,    dim3(NB_FB + NB_ASM), dim3(256), 0, stream, p);
}